// Round 2
// baseline (2043.427 us; speedup 1.0000x reference)
//
#include <hip/hip_runtime.h>

#define NATOMS 300000
#define NCOLS 8
#define VOCABSZ 4096
#define DCOL 32
#define HIDDIM 256
#define NBONDS 320000
#define NGRAPHS 6000
#define NSTEPS 3

constexpr int MP = 300032;             // atoms padded to multiple of 64
constexpr int MTILES64 = MP / 64;      // 4688 gemm blocks
constexpr int HSTR = 2 * HIDDIM;       // interleaved h row: [hi256|lo256]
constexpr int XSTR = 2 * DCOL;         // interleaved x row: [hi32|lo32]

typedef _Float16 f16;
typedef _Float16 f16x8 __attribute__((ext_vector_type(8)));
typedef float f32x4 __attribute__((ext_vector_type(4)));

constexpr float LO_SCALE = 2048.0f;      // 2^11: keeps lo parts fp16-normal
constexpr float INV_LO   = 1.0f / 2048.0f;

__device__ __forceinline__ void split2(float x, f16& h, f16& l) {
    h = (f16)x;
    l = (f16)((x - (float)h) * LO_SCALE);
}

// 16B-unit XOR swizzle (r10: measured ZERO bank conflicts). Involution in q.
__device__ __forceinline__ int swz(int row, int q) {
    return (row * 4 + (q ^ ((row >> 1) & 3))) * 8;
}

// Async global->LDS DMA, 16B per lane per wave-instruction.
__device__ __forceinline__ void dma16(const f16* g, f16* l) {
    __builtin_amdgcn_global_load_lds(
        (const __attribute__((address_space(1))) uint32_t*)g,
        (__attribute__((address_space(3))) uint32_t*)l, 16, 0, 0);
}

// ---------------------------------------------------------------------------
static void* g_pool = nullptr;
__attribute__((constructor)) static void alloc_pool() {
    void* p = nullptr;
    if (hipMalloc(&p, (size_t)1024 * 1024 * 1024) == hipSuccess) {
        hipMemset(p, 0, (size_t)1024 * 1024 * 1024);
        g_pool = p;
    }
}

// ---------------------------------------------------------------------------
__global__ void fill_kernel(float* out, float v, int n) {
    int i = blockIdx.x * blockDim.x + threadIdx.x;
    if (i < n) out[i] = v;
}

// ---------------------------------------------------------------------------
__global__ void build_edges_kernel(const int* __restrict__ bf, int* __restrict__ esrc,
                                   int* __restrict__ nxt, int* head) {
    int e = blockIdx.x * blockDim.x + threadIdx.x;
    if (e >= 2 * NBONDS) return;
    int src, dst;
    if (e < NBONDS) { src = bf[e * 3 + 0]; dst = bf[e * 3 + 1]; }
    else { int i = e - NBONDS; src = bf[i * 3 + 1]; dst = bf[i * 3 + 0]; }
    esrc[e] = src;
    nxt[e] = atomicExch(&head[dst], e);
}

// ---------------------------------------------------------------------------
// Weight pack: split2 + FRAGMENT-MAJOR layout so a wave's MFMA B-fragment is
// one fully-coalesced 1KB load straight from L2 (no LDS for B at all).
// element (n,k) -> ((n>>4)*(K/8) + (k>>3))*128 + (n&15)*8 + (k&7)
__global__ void bpack_kernel(const float* __restrict__ W, f16* __restrict__ Bh,
                             f16* __restrict__ Bl, int K, int n_total) {
    int i = blockIdx.x * blockDim.x + threadIdx.x;
    if (i >= n_total) return;
    int n = i / K, k = i - n * K;
    float v = W[(size_t)n * K + k];
    int pidx = (((n >> 4) * (K >> 3) + (k >> 3)) * 16 + (n & 15)) * 8 + (k & 7);
    f16 hi, lo;
    split2(v, hi, lo);
    Bh[pidx] = hi;
    Bl[pidx] = lo;
}

__global__ void bsum_kernel(const float* __restrict__ a, const float* __restrict__ b,
                            float* __restrict__ o) {
    int i = threadIdx.x;
    o[i] = a[i] + b[i];
}

// ---------------------------------------------------------------------------
// Embedding -> interleaved x rows [hi32|lo32].
__global__ void embed_kernel(const int* __restrict__ af, const float* __restrict__ emb,
                             f16* __restrict__ x) {
    int gid = blockIdx.x * blockDim.x + threadIdx.x;
    int i = gid >> 5, k = gid & 31;
    if (i >= NATOMS) return;
    float s = 0.0f;
#pragma unroll
    for (int c = 0; c < NCOLS; c++) {
        int v = af[i * NCOLS + c];
        int idx = v & (VOCABSZ - 1);
        if (v >= 999999999) idx = 0;
        s += emb[((size_t)c * VOCABSZ + idx) * DCOL + k];
    }
    f16 hi, lo;
    split2(s, hi, lo);
    x[(size_t)i * XSTR + k] = hi;
    x[(size_t)i * XSTR + DCOL + k] = lo;
}

// ---------------------------------------------------------------------------
// Aggregation over interleaved rows (unchanged).
__global__ void agg_kernel(const f16* __restrict__ H, f16* __restrict__ G,
                           const int* __restrict__ head, const int* __restrict__ nxt,
                           const int* __restrict__ esrc) {
    int wid = (blockIdx.x * blockDim.x + threadIdx.x) >> 6;
    int lane = threadIdx.x & 63;
    if (wid >= NATOMS) return;
    float a0 = 0.f, a1 = 0.f, a2 = 0.f, a3 = 0.f,
          a4 = 0.f, a5 = 0.f, a6 = 0.f, a7 = 0.f;
    int e = head[wid];
    while (e >= 0) {
        int src = esrc[e];
        const f16x8 v = *(const f16x8*)(H + (size_t)src * HSTR + lane * 8);
        a0 += (float)v[0]; a1 += (float)v[1]; a2 += (float)v[2]; a3 += (float)v[3];
        a4 += (float)v[4]; a5 += (float)v[5]; a6 += (float)v[6]; a7 += (float)v[7];
        e = nxt[e];
    }
    const bool isLo = lane >= 32;
    if (isLo) {
        a0 *= INV_LO; a1 *= INV_LO; a2 *= INV_LO; a3 *= INV_LO;
        a4 *= INV_LO; a5 *= INV_LO; a6 *= INV_LO; a7 *= INV_LO;
    }
    float s0 = a0 + __shfl_xor(a0, 32, 64);
    float s1 = a1 + __shfl_xor(a1, 32, 64);
    float s2 = a2 + __shfl_xor(a2, 32, 64);
    float s3 = a3 + __shfl_xor(a3, 32, 64);
    float s4 = a4 + __shfl_xor(a4, 32, 64);
    float s5 = a5 + __shfl_xor(a5, 32, 64);
    float s6 = a6 + __shfl_xor(a6, 32, 64);
    float s7 = a7 + __shfl_xor(a7, 32, 64);
    f16x8 o;
#define EMIT(J, S)                                                    \
    {                                                                 \
        const f16 hv = (f16)(S);                                      \
        o[J] = isLo ? (f16)(((S) - (float)hv) * LO_SCALE) : hv;       \
    }
    EMIT(0, s0) EMIT(1, s1) EMIT(2, s2) EMIT(3, s3)
    EMIT(4, s4) EMIT(5, s5) EMIT(6, s6) EMIT(7, s7)
#undef EMIT
    *(f16x8*)(G + (size_t)wid * HSTR + lane * 8) = o;
}

// ---------------------------------------------------------------------------
// MFMA GEMM v3: B direct-to-register from packed L2-resident layout (zero LDS
// for B: removes 32KB ds_write + 32KB ds_read per stage — the LDS pipe was
// ~2x the MFMA pipe). A stays via global_load_lds (HBM-coalesced 1KB),
// TRIPLE-buffered (24KB LDS), depth-2 prefetch, raw s_barrier + counted
// vmcnt (never drains B/next-A loads). Register-load readiness is left to
// the compiler's precise auto-waitcnts; the ONLY manual wait is the
// dma->barrier edge. Count math (set-based, vmcnt retires in-order): at the
// wait point the 10 newest VMEM ops are {bl(s)·4, bh(s)·4, A(s+1)·2}; all
// older ops — including stage-s A dma — must be retired -> vmcnt(10).
// Epilogue (no next-issues): {bl·4, bh·4} -> vmcnt(8). lgkmcnt(0) before the
// barrier closes the ds_read-in-flight vs next-dma-write race.
// __launch_bounds__(256,2) STRUCTURAL (r13/r15 lessons).
template <bool HAS_A2, bool RELU, int K>
__global__ __launch_bounds__(256, 2) void mfma_gemm(
    const f16* __restrict__ A1, const f16* __restrict__ A2,
    const f16* __restrict__ B1h, const f16* __restrict__ B1l,
    const f16* __restrict__ B2h, const f16* __restrict__ B2l,
    const float* __restrict__ bias, f16* __restrict__ C) {
    constexpr int ABUF = 4096;                 // halves per A stage buf (hi+lo)
    __shared__ __align__(16) f16 lds[3 * ABUF];   // 24 KB

    const int t = threadIdx.x;
    const int m0 = blockIdx.x * 64;
    const int lane = t & 63;
    const int wid = t >> 6;     // 0..3
    const int wn = wid * 64;    // wave's column origin
    const int quad = lane >> 4;
    const int l16 = lane & 15;

    // A staging geometry (verified): lane -> (row, inverse-swizzled quad)
    const int ra_ = wid * 16 + (lane >> 2);
    const int qs_ = (lane & 3) ^ ((ra_ >> 1) & 3);
    const int ko_ = qs_ * 8;

    f32x4 acch[4][4], accl[4][4];   // [mt][nt]
#pragma unroll
    for (int a = 0; a < 4; a++)
#pragma unroll
        for (int b = 0; b < 4; b++) {
            acch[a][b] = (f32x4){0.f, 0.f, 0.f, 0.f};
            accl[a][b] = (f32x4){0.f, 0.f, 0.f, 0.f};
        }

    constexpr int NMAT = HAS_A2 ? 2 : 1;
    constexpr int NST = (K / 32) * NMAT;
    constexpr int K8 = K / 8;

    f16x8 rbh[4], rbhN[4], rbl[4];       // B frags: current-hi, next-hi, cur-lo

#define ISSUE_A(S, BI)                                                         \
    {                                                                          \
        const int mat_ = HAS_A2 ? ((S) & 1) : 0;                               \
        const int kb_ = (HAS_A2 ? ((S) >> 1) : (S)) * 32;                      \
        const f16* A_ = (mat_ == 0) ? A1 : A2;                                 \
        f16* const dst_ = lds + (BI) * ABUF + wid * 512;                       \
        const size_t arow_ = (size_t)(m0 + ra_) * (2 * K) + kb_ + ko_;         \
        dma16(A_ + arow_, dst_);                                               \
        dma16(A_ + arow_ + K, dst_ + 2048);                                    \
    }

#define LOAD_B4(S, PH, DEST)                                                   \
    {                                                                          \
        const int mat_ = HAS_A2 ? ((S) & 1) : 0;                               \
        const int kb8_ = (HAS_A2 ? ((S) >> 1) : (S)) * 4;                      \
        const f16* Bp_ = (PH) ? (mat_ == 0 ? B1h : B2h)                        \
                              : (mat_ == 0 ? B1l : B2l);                       \
        const f16x8* pb_ =                                                     \
            (const f16x8*)(Bp_ + ((size_t)(wn >> 4) * K8 + kb8_) * 128);       \
        DEST[0] = pb_[lane];                                                   \
        DEST[1] = pb_[lane + K8 * 16];                                         \
        DEST[2] = pb_[lane + K8 * 32];                                         \
        DEST[3] = pb_[lane + K8 * 48];                                         \
    }

    // ---- prologue: A depth-2 into bufs 0/1, bh(0) into rbhN ----
    ISSUE_A(0, 0);
    asm volatile("" ::: "memory");
    if (NST > 1) ISSUE_A(1, 1);
    asm volatile("" ::: "memory");
    LOAD_B4(0, 1, rbhN);
    asm volatile("" ::: "memory");

    int bufs = 0;   // s % 3
    for (int s = 0; s < NST - 1; s++) {
        LOAD_B4(s, 0, rbl);                               // bl(s), newest
        // A(s) must be retired before the barrier; 10 newest may remain.
        asm volatile("s_waitcnt vmcnt(10) lgkmcnt(0)" ::: "memory");
        __builtin_amdgcn_s_barrier();
        if (s + 2 < NST) {
            int bI = bufs + 2; if (bI >= 3) bI -= 3;
            ISSUE_A(s + 2, bI);
        }
        const f16* sAh = lds + bufs * ABUF;
        const f16* sAl = sAh + 2048;
        f16x8 fah[4], fal[4];
#pragma unroll
        for (int mt = 0; mt < 4; mt++) {
            const int src = swz(mt * 16 + l16, quad);
            fah[mt] = *(const f16x8*)(sAh + src);
            fal[mt] = *(const f16x8*)(sAl + src);
        }
        // bh(s) regs ready (compiler inserts the precise vmcnt): copy, then
        // reuse rbhN for bh(s+1).
#pragma unroll
        for (int i = 0; i < 4; i++) rbh[i] = rbhN[i];
        LOAD_B4(s + 1, 1, rbhN);
#pragma unroll
        for (int nt = 0; nt < 4; nt++)
#pragma unroll
            for (int mt = 0; mt < 4; mt++)
                acch[mt][nt] = __builtin_amdgcn_mfma_f32_16x16x32_f16(fah[mt], rbh[nt], acch[mt][nt], 0, 0, 0);
#pragma unroll
        for (int nt = 0; nt < 4; nt++)
#pragma unroll
            for (int mt = 0; mt < 4; mt++)
                accl[mt][nt] = __builtin_amdgcn_mfma_f32_16x16x32_f16(fal[mt], rbh[nt], accl[mt][nt], 0, 0, 0);
#pragma unroll
        for (int nt = 0; nt < 4; nt++)
#pragma unroll
            for (int mt = 0; mt < 4; mt++)
                accl[mt][nt] = __builtin_amdgcn_mfma_f32_16x16x32_f16(fah[mt], rbl[nt], accl[mt][nt], 0, 0, 0);
        bufs = (bufs == 2) ? 0 : bufs + 1;
    }

    // ---- epilogue stage s = NST-1 (no next-issues; allow {bh4, bl4}) ----
    {
        const int s = NST - 1;
        LOAD_B4(s, 0, rbl);
        asm volatile("s_waitcnt vmcnt(8) lgkmcnt(0)" ::: "memory");
        __builtin_amdgcn_s_barrier();
        const f16* sAh = lds + bufs * ABUF;
        const f16* sAl = sAh + 2048;
        f16x8 fah[4], fal[4];
#pragma unroll
        for (int mt = 0; mt < 4; mt++) {
            const int src = swz(mt * 16 + l16, quad);
            fah[mt] = *(const f16x8*)(sAh + src);
            fal[mt] = *(const f16x8*)(sAl + src);
        }
#pragma unroll
        for (int i = 0; i < 4; i++) rbh[i] = rbhN[i];
#pragma unroll
        for (int nt = 0; nt < 4; nt++)
#pragma unroll
            for (int mt = 0; mt < 4; mt++)
                acch[mt][nt] = __builtin_amdgcn_mfma_f32_16x16x32_f16(fah[mt], rbh[nt], acch[mt][nt], 0, 0, 0);
#pragma unroll
        for (int nt = 0; nt < 4; nt++)
#pragma unroll
            for (int mt = 0; mt < 4; mt++)
                accl[mt][nt] = __builtin_amdgcn_mfma_f32_16x16x32_f16(fal[mt], rbh[nt], accl[mt][nt], 0, 0, 0);
#pragma unroll
        for (int nt = 0; nt < 4; nt++)
#pragma unroll
            for (int mt = 0; mt < 4; mt++)
                accl[mt][nt] = __builtin_amdgcn_mfma_f32_16x16x32_f16(fah[mt], rbl[nt], accl[mt][nt], 0, 0, 0);
    }
#undef ISSUE_A
#undef LOAD_B4

#pragma unroll
    for (int mt = 0; mt < 4; mt++) {
#pragma unroll
        for (int nt = 0; nt < 4; nt++) {
            const int col = wn + nt * 16 + l16;
            const float bv = bias[col];
#pragma unroll
            for (int r = 0; r < 4; r++) {
                const int row = m0 + mt * 16 + quad * 4 + r;
                float v = acch[mt][nt][r] + accl[mt][nt][r] * INV_LO + bv;
                if (RELU) v = fmaxf(v, 0.f);
                f16 hi, lo;
                split2(v, hi, lo);
                C[(size_t)row * HSTR + col] = hi;
                C[(size_t)row * HSTR + HIDDIM + col] = lo;
            }
        }
    }
}

// ---------------------------------------------------------------------------
// Segment-mean of interleaved final h -> G[6000][256] fp32.
__global__ void readout_mean_kernel(const f16* __restrict__ H,
                                    const int* __restrict__ scopes, float* __restrict__ G) {
    int g = blockIdx.x;
    int n = threadIdx.x;
    int start = scopes[g * 2 + 0];
    int len = scopes[g * 2 + 1];
    float s = 0.f;
    for (int j = 0; j < len; j++) {
        const f16* row = H + (size_t)(start + j) * HSTR;
        s += (float)row[n] + (float)row[HIDDIM + n] * INV_LO;
    }
    int d = len > 1 ? len : 1;
    G[(size_t)g * HIDDIM + n] = s / (float)d;
}

// ---------------------------------------------------------------------------
// Tiny fp32 GEMM: out[g][n] = G[g][:] . W_out[n][:] + b_out[n], g<6000.
__global__ __launch_bounds__(256) void out_gemm_kernel(
    const float* __restrict__ G, const float* __restrict__ W,
    const float* __restrict__ bias, float* __restrict__ out) {
    __shared__ float sG[16 * 256];
    const int g0 = blockIdx.x * 16;
    const int t = threadIdx.x;
#pragma unroll
    for (int i = 0; i < 16; i++) sG[i * 256 + t] = G[(size_t)(g0 + i) * 256 + t];
    __syncthreads();
    const float bv = bias[t];
    const float* wrow = W + (size_t)t * 256;   // W[n][k] row-major
    float acc[16];
#pragma unroll
    for (int g = 0; g < 16; g++) acc[g] = 0.f;
    for (int k = 0; k < 256; k += 4) {
        const float4 w = *(const float4*)(wrow + k);
#pragma unroll
        for (int g = 0; g < 16; g++) {
            const float4 a = *(const float4*)(sG + g * 256 + k);   // broadcast
            acc[g] = fmaf(a.x, w.x, acc[g]);
            acc[g] = fmaf(a.y, w.y, acc[g]);
            acc[g] = fmaf(a.z, w.z, acc[g]);
            acc[g] = fmaf(a.w, w.w, acc[g]);
        }
    }
#pragma unroll
    for (int g = 0; g < 16; g++) out[(size_t)(g0 + g) * 256 + t] = acc[g] + bv;
}

// ---------------------------------------------------------------------------
extern "C" void kernel_launch(void* const* d_in, const int* in_sizes, int n_in,
                              void* d_out, int out_size, void* d_ws, size_t ws_size,
                              hipStream_t stream) {
    const int* a_features = (const int*)d_in[0];
    const int* b_features = (const int*)d_in[1];
    const int* a_scopes   = (const int*)d_in[2];
    const float* emb      = (const float*)d_in[3];
    const float* W_in     = (const float*)d_in[4];
    const float* b_in     = (const float*)d_in[5];
    const float* W_self   = (const float*)d_in[6];
    const float* b_self   = (const float*)d_in[7];
    const float* W_neigh  = (const float*)d_in[8];
    const float* b_neigh  = (const float*)d_in[9];
    const float* W_out    = (const float*)d_in[10];
    const float* b_out    = (const float*)d_in[11];

    if (g_pool == nullptr) {
        fill_kernel<<<(out_size + 255) / 256, 256, 0, stream>>>(
            (float*)d_out, 77777.0f, out_size);
        return;
    }

    // ---- pool layout (halves); interleaved h buffers [hi256|lo256] ----
    f16* p = (f16*)g_pool;
    const size_t HB2 = (size_t)MP * HSTR;        // 153,616,384 halves / buffer
    f16* bufA = p;
    f16* bufB = p + HB2;
    f16* bufC = p + 2 * HB2;
    f16* xbuf = p + 3 * HB2;                     // [MP][64] interleaved
    f16* Winh = xbuf + (size_t)MP * XSTR;        // packed fragment-major
    f16* Winl = Winh + HIDDIM * DCOL;
    f16* Wsh  = Winl + HIDDIM * DCOL;
    f16* Wsl  = Wsh + HIDDIM * HIDDIM;
    f16* Wnh  = Wsl + HIDDIM * HIDDIM;
    f16* Wnl  = Wnh + HIDDIM * HIDDIM;
    float* Gmean = (float*)(Wnl + HIDDIM * HIDDIM);        // [6000][256] fp32
    float* bsum  = Gmean + (size_t)NGRAPHS * HIDDIM;
    int* esrc = (int*)(bsum + HIDDIM);
    int* nxt  = esrc + 2 * NBONDS;
    int* head = nxt + 2 * NBONDS;

    constexpr int NPAD = MP - NATOMS;            // 32 pad rows

    // ---- setup (identical every launch) ----
    hipMemsetAsync(head, 0xFF, (size_t)MP * sizeof(int), stream);
    build_edges_kernel<<<(2 * NBONDS + 255) / 256, 256, 0, stream>>>(b_features, esrc, nxt, head);
    bpack_kernel<<<(HIDDIM * DCOL + 255) / 256, 256, 0, stream>>>(W_in, Winh, Winl, DCOL, HIDDIM * DCOL);
    bpack_kernel<<<(HIDDIM * HIDDIM + 255) / 256, 256, 0, stream>>>(W_self, Wsh, Wsl, HIDDIM, HIDDIM * HIDDIM);
    bpack_kernel<<<(HIDDIM * HIDDIM + 255) / 256, 256, 0, stream>>>(W_neigh, Wnh, Wnl, HIDDIM, HIDDIM * HIDDIM);
    bsum_kernel<<<1, HIDDIM, 0, stream>>>(b_self, b_neigh, bsum);

    // Zero padding rows (pool is persistent; keeps pad lanes deterministic).
    constexpr int PADH = NPAD * HSTR / 2;        // halves -> floats
    fill_kernel<<<(PADH + 255) / 256, 256, 0, stream>>>((float*)(bufA + (size_t)NATOMS * HSTR), 0.f, PADH);
    fill_kernel<<<(PADH + 255) / 256, 256, 0, stream>>>((float*)(bufB + (size_t)NATOMS * HSTR), 0.f, PADH);
    fill_kernel<<<(PADH + 255) / 256, 256, 0, stream>>>((float*)(bufC + (size_t)NATOMS * HSTR), 0.f, PADH);
    constexpr int PADX = NPAD * XSTR / 2;
    fill_kernel<<<(PADX + 255) / 256, 256, 0, stream>>>((float*)(xbuf + (size_t)NATOMS * XSTR), 0.f, PADX);

    // ---- embedding + input linear -> h (bufA) ----
    embed_kernel<<<(NATOMS * DCOL + 255) / 256, 256, 0, stream>>>(a_features, emb, xbuf);
    mfma_gemm<false, false, DCOL><<<MTILES64, 256, 0, stream>>>(
        xbuf, nullptr, Winh, Winl, nullptr, nullptr, b_in, bufA);

    // ---- 3 message-passing steps with rotating buffers ----
    f16* h  = bufA;
    f16* g  = bufB;
    f16* hn = bufC;
    for (int s = 0; s < NSTEPS; s++) {
        agg_kernel<<<NATOMS / 4, 256, 0, stream>>>(h, g, head, nxt, esrc);
        mfma_gemm<true, true, HIDDIM><<<MTILES64, 256, 0, stream>>>(
            h, g, Wsh, Wsl, Wnh, Wnl, bsum, hn);
        f16* old = h;
        h = hn; hn = g; g = old;
    }

    // ---- mean first (linearity), then tiny output linear ----
    readout_mean_kernel<<<NGRAPHS, 256, 0, stream>>>(h, a_scopes, Gmean);
    out_gemm_kernel<<<NGRAPHS / 16, 256, 0, stream>>>(Gmean, W_out, b_out, (float*)d_out);
}

// Round 3
// 1944.328 us; speedup vs baseline: 1.0510x; 1.0510x over previous
//
#include <hip/hip_runtime.h>

#define NATOMS 300000
#define NCOLS 8
#define VOCABSZ 4096
#define DCOL 32
#define HIDDIM 256
#define NBONDS 320000
#define NGRAPHS 6000
#define NSTEPS 3

constexpr int MP = 300032;             // atoms padded to multiple of 128
constexpr int MTILES128 = MP / 128;    // 2344 gemm blocks
constexpr int HSTR = 2 * HIDDIM;       // interleaved h row: [hi256|lo256]
constexpr int XSTR = 2 * DCOL;         // interleaved x row: [hi32|lo32]

typedef _Float16 f16;
typedef _Float16 f16x8 __attribute__((ext_vector_type(8)));
typedef float f32x4 __attribute__((ext_vector_type(4)));

constexpr float LO_SCALE = 2048.0f;      // 2^11: keeps lo parts fp16-normal
constexpr float INV_LO   = 1.0f / 2048.0f;

__device__ __forceinline__ void split2(float x, f16& h, f16& l) {
    h = (f16)x;
    l = (f16)((x - (float)h) * LO_SCALE);
}

// 16B-unit XOR swizzle (r10: measured ZERO bank conflicts). Involution in q.
__device__ __forceinline__ int swz(int row, int q) {
    return (row * 4 + (q ^ ((row >> 1) & 3))) * 8;
}

// Async global->LDS DMA, 16B per lane per wave-instruction.
__device__ __forceinline__ void dma16(const f16* g, f16* l) {
    __builtin_amdgcn_global_load_lds(
        (const __attribute__((address_space(1))) uint32_t*)g,
        (__attribute__((address_space(3))) uint32_t*)l, 16, 0, 0);
}

// ---------------------------------------------------------------------------
static void* g_pool = nullptr;
__attribute__((constructor)) static void alloc_pool() {
    void* p = nullptr;
    if (hipMalloc(&p, (size_t)1024 * 1024 * 1024) == hipSuccess) {
        hipMemset(p, 0, (size_t)1024 * 1024 * 1024);
        g_pool = p;
    }
}

// ---------------------------------------------------------------------------
__global__ void fill_kernel(float* out, float v, int n) {
    int i = blockIdx.x * blockDim.x + threadIdx.x;
    if (i < n) out[i] = v;
}

// ---------------------------------------------------------------------------
__global__ void build_edges_kernel(const int* __restrict__ bf, int* __restrict__ esrc,
                                   int* __restrict__ nxt, int* head) {
    int e = blockIdx.x * blockDim.x + threadIdx.x;
    if (e >= 2 * NBONDS) return;
    int src, dst;
    if (e < NBONDS) { src = bf[e * 3 + 0]; dst = bf[e * 3 + 1]; }
    else { int i = e - NBONDS; src = bf[i * 3 + 1]; dst = bf[i * 3 + 0]; }
    esrc[e] = src;
    nxt[e] = atomicExch(&head[dst], e);
}

// ---------------------------------------------------------------------------
__global__ void wsplit_kernel(const float* __restrict__ W, f16* __restrict__ Wh,
                              f16* __restrict__ Wl, int n) {
    int i = blockIdx.x * blockDim.x + threadIdx.x;
    if (i >= n) return;
    split2(W[i], Wh[i], Wl[i]);
}

__global__ void bsum_kernel(const float* __restrict__ a, const float* __restrict__ b,
                            float* __restrict__ o) {
    int i = threadIdx.x;
    o[i] = a[i] + b[i];
}

// ---------------------------------------------------------------------------
// Embedding -> interleaved x rows [hi32|lo32].
__global__ void embed_kernel(const int* __restrict__ af, const float* __restrict__ emb,
                             f16* __restrict__ x) {
    int gid = blockIdx.x * blockDim.x + threadIdx.x;
    int i = gid >> 5, k = gid & 31;
    if (i >= NATOMS) return;
    float s = 0.0f;
#pragma unroll
    for (int c = 0; c < NCOLS; c++) {
        int v = af[i * NCOLS + c];
        int idx = v & (VOCABSZ - 1);
        if (v >= 999999999) idx = 0;
        s += emb[((size_t)c * VOCABSZ + idx) * DCOL + k];
    }
    f16 hi, lo;
    split2(s, hi, lo);
    x[(size_t)i * XSTR + k] = hi;
    x[(size_t)i * XSTR + DCOL + k] = lo;
}

// ---------------------------------------------------------------------------
// Aggregation over interleaved rows (unchanged, proven).
__global__ void agg_kernel(const f16* __restrict__ H, f16* __restrict__ G,
                           const int* __restrict__ head, const int* __restrict__ nxt,
                           const int* __restrict__ esrc) {
    int wid = (blockIdx.x * blockDim.x + threadIdx.x) >> 6;
    int lane = threadIdx.x & 63;
    if (wid >= NATOMS) return;
    float a0 = 0.f, a1 = 0.f, a2 = 0.f, a3 = 0.f,
          a4 = 0.f, a5 = 0.f, a6 = 0.f, a7 = 0.f;
    int e = head[wid];
    while (e >= 0) {
        int src = esrc[e];
        const f16x8 v = *(const f16x8*)(H + (size_t)src * HSTR + lane * 8);
        a0 += (float)v[0]; a1 += (float)v[1]; a2 += (float)v[2]; a3 += (float)v[3];
        a4 += (float)v[4]; a5 += (float)v[5]; a6 += (float)v[6]; a7 += (float)v[7];
        e = nxt[e];
    }
    const bool isLo = lane >= 32;
    if (isLo) {
        a0 *= INV_LO; a1 *= INV_LO; a2 *= INV_LO; a3 *= INV_LO;
        a4 *= INV_LO; a5 *= INV_LO; a6 *= INV_LO; a7 *= INV_LO;
    }
    float s0 = a0 + __shfl_xor(a0, 32, 64);
    float s1 = a1 + __shfl_xor(a1, 32, 64);
    float s2 = a2 + __shfl_xor(a2, 32, 64);
    float s3 = a3 + __shfl_xor(a3, 32, 64);
    float s4 = a4 + __shfl_xor(a4, 32, 64);
    float s5 = a5 + __shfl_xor(a5, 32, 64);
    float s6 = a6 + __shfl_xor(a6, 32, 64);
    float s7 = a7 + __shfl_xor(a7, 32, 64);
    f16x8 o;
#define EMIT(J, S)                                                    \
    {                                                                 \
        const f16 hv = (f16)(S);                                      \
        o[J] = isLo ? (f16)(((S) - (float)hv) * LO_SCALE) : hv;       \
    }
    EMIT(0, s0) EMIT(1, s1) EMIT(2, s2) EMIT(3, s3)
    EMIT(4, s4) EMIT(5, s5) EMIT(6, s6) EMIT(7, s7)
#undef EMIT
    *(f16x8*)(G + (size_t)wid * HSTR + lane * 8) = o;
}

// ---------------------------------------------------------------------------
// MFMA GEMM v4: R1 structure (global_load_lds for A AND B, dbuf, one
// __syncthreads per stage, DMA(s+1) issued right after the barrier) scaled to
// BM=128 x BN=256, 512 threads / 8 waves (2M x 4N). Why: with BK=32 the
// per-stage MFMA work is now ~1860 cyc >> HBM latency (~900), so the
// depth-1 prefetch fully covers the DMA and the __syncthreads drain finds an
// empty queue (R1's per-stage ~400cy drain stall was the 332 vs ~200 gap).
// LDS bytes/MFMA also drops 542->458 (A-frag reads amortize over 2x MFMA),
// putting the LDS pipe (~1570cy/stage) under the MFMA pipe. 96KB dbuf ->
// 1 block/CU, 2 waves/SIMD. Swizzle + staging geometry verified in r10/R1;
// B's +128-row block keeps the same inverse-swizzle bits (128 % 8 == 0).
template <bool HAS_A2, bool RELU, int K>
__global__ __launch_bounds__(512, 2) void mfma_gemm(
    const f16* __restrict__ A1, const f16* __restrict__ A2,
    const f16* __restrict__ B1h, const f16* __restrict__ B1l,
    const f16* __restrict__ B2h, const f16* __restrict__ B2l,
    const float* __restrict__ bias, f16* __restrict__ C) {
    // per-stage buffer (halves): [A-hi 128x32][A-lo][B-hi 256x32][B-lo]
    constexpr int OAH = 0, OAL = 4096, OBH = 8192, OBL = 16384, BUFH = 24576;
    __shared__ __align__(16) f16 lds[2 * BUFH];   // 96 KB

    const int t = threadIdx.x;
    const int m0 = blockIdx.x * 128;
    const int lane = t & 63;
    const int wid = t >> 6;        // 0..7
    const int wr = wid >> 2;       // 0..1 : row  half (64 rows)
    const int wc = wid & 3;        // 0..3 : col quarter (64 cols)
    const int quad = lane >> 4;
    const int l16 = lane & 15;

    // staging geometry: wave w stages rows [w*16, w*16+16), lane -> (row, q)
    const int ra_ = wid * 16 + (lane >> 2);
    const int qs_ = (lane & 3) ^ ((ra_ >> 1) & 3);   // inverse-swizzled quad
    const int ko_ = qs_ * 8;

    f32x4 acch[4][4], accl[4][4];   // [mt][nt]
#pragma unroll
    for (int a = 0; a < 4; a++)
#pragma unroll
        for (int b = 0; b < 4; b++) {
            acch[a][b] = (f32x4){0.f, 0.f, 0.f, 0.f};
            accl[a][b] = (f32x4){0.f, 0.f, 0.f, 0.f};
        }

    constexpr int NMAT = HAS_A2 ? 2 : 1;
    constexpr int NST = (K / 32) * NMAT;

#define ISSUE_STAGE(S, BUF)                                                    \
    {                                                                          \
        const int mat_ = HAS_A2 ? ((S) & 1) : 0;                               \
        const int kb_ = (HAS_A2 ? ((S) >> 1) : (S)) * 32;                      \
        const f16* A_ = (mat_ == 0) ? A1 : A2;                                 \
        const f16* Bh_ = (mat_ == 0) ? B1h : B2h;                              \
        const f16* Bl_ = (mat_ == 0) ? B1l : B2l;                              \
        f16* const dst_ = lds + (BUF) * BUFH + wid * 512;                      \
        const size_t arow_ = (size_t)(m0 + ra_) * (2 * K) + kb_ + ko_;         \
        dma16(A_ + arow_, dst_ + OAH);                                         \
        dma16(A_ + arow_ + K, dst_ + OAL);                                     \
        const size_t brow_ = (size_t)ra_ * K + kb_ + ko_;                      \
        dma16(Bh_ + brow_, dst_ + OBH);                                        \
        dma16(Bh_ + brow_ + (size_t)128 * K, dst_ + OBH + 4096);               \
        dma16(Bl_ + brow_, dst_ + OBL);                                        \
        dma16(Bl_ + brow_ + (size_t)128 * K, dst_ + OBL + 4096);               \
    }

    ISSUE_STAGE(0, 0);

    for (int s = 0; s < NST; s++) {
        // __syncthreads: vmcnt(0)+lgkmcnt(0)+barrier. The only outstanding
        // VMEM here is DMA(s), issued a full stage (~1860cy) ago -> no stall.
        __syncthreads();
        if (s + 1 < NST) ISSUE_STAGE(s + 1, (s + 1) & 1);

        const f16* cb = lds + (s & 1) * BUFH;
        const f16* sAh = cb + OAH;
        const f16* sAl = cb + OAL;
        const f16* sBh = cb + OBH;
        const f16* sBl = cb + OBL;

        f16x8 fah[4], fal[4];
#pragma unroll
        for (int mt = 0; mt < 4; mt++) {
            const int src = swz(wr * 64 + mt * 16 + l16, quad);
            fah[mt] = *(const f16x8*)(sAh + src);
            fal[mt] = *(const f16x8*)(sAl + src);
        }
#pragma unroll
        for (int nt = 0; nt < 4; nt++) {
            const int src = swz(wc * 64 + nt * 16 + l16, quad);
            const f16x8 bh = *(const f16x8*)(sBh + src);
            const f16x8 bl = *(const f16x8*)(sBl + src);
#pragma unroll
            for (int mt = 0; mt < 4; mt++) {
                acch[mt][nt] = __builtin_amdgcn_mfma_f32_16x16x32_f16(fah[mt], bh, acch[mt][nt], 0, 0, 0);
                accl[mt][nt] = __builtin_amdgcn_mfma_f32_16x16x32_f16(fah[mt], bl, accl[mt][nt], 0, 0, 0);
                accl[mt][nt] = __builtin_amdgcn_mfma_f32_16x16x32_f16(fal[mt], bh, accl[mt][nt], 0, 0, 0);
            }
        }
    }
#undef ISSUE_STAGE

#pragma unroll
    for (int mt = 0; mt < 4; mt++) {
#pragma unroll
        for (int nt = 0; nt < 4; nt++) {
            const int col = wc * 64 + nt * 16 + l16;
            const float bv = bias[col];
#pragma unroll
            for (int r = 0; r < 4; r++) {
                const int row = m0 + wr * 64 + mt * 16 + quad * 4 + r;
                float v = acch[mt][nt][r] + accl[mt][nt][r] * INV_LO + bv;
                if (RELU) v = fmaxf(v, 0.f);
                f16 hi, lo;
                split2(v, hi, lo);
                C[(size_t)row * HSTR + col] = hi;
                C[(size_t)row * HSTR + HIDDIM + col] = lo;
            }
        }
    }
}

// ---------------------------------------------------------------------------
// Segment-mean of interleaved final h -> G[6000][256] fp32.
__global__ void readout_mean_kernel(const f16* __restrict__ H,
                                    const int* __restrict__ scopes, float* __restrict__ G) {
    int g = blockIdx.x;
    int n = threadIdx.x;
    int start = scopes[g * 2 + 0];
    int len = scopes[g * 2 + 1];
    float s = 0.f;
    for (int j = 0; j < len; j++) {
        const f16* row = H + (size_t)(start + j) * HSTR;
        s += (float)row[n] + (float)row[HIDDIM + n] * INV_LO;
    }
    int d = len > 1 ? len : 1;
    G[(size_t)g * HIDDIM + n] = s / (float)d;
}

// ---------------------------------------------------------------------------
// Tiny fp32 GEMM: out[g][n] = G[g][:] . W_out[n][:] + b_out[n], g<6000.
__global__ __launch_bounds__(256) void out_gemm_kernel(
    const float* __restrict__ G, const float* __restrict__ W,
    const float* __restrict__ bias, float* __restrict__ out) {
    __shared__ float sG[16 * 256];
    const int g0 = blockIdx.x * 16;
    const int t = threadIdx.x;
#pragma unroll
    for (int i = 0; i < 16; i++) sG[i * 256 + t] = G[(size_t)(g0 + i) * 256 + t];
    __syncthreads();
    const float bv = bias[t];
    const float* wrow = W + (size_t)t * 256;   // W[n][k] row-major
    float acc[16];
#pragma unroll
    for (int g = 0; g < 16; g++) acc[g] = 0.f;
    for (int k = 0; k < 256; k += 4) {
        const float4 w = *(const float4*)(wrow + k);
#pragma unroll
        for (int g = 0; g < 16; g++) {
            const float4 a = *(const float4*)(sG + g * 256 + k);   // broadcast
            acc[g] = fmaf(a.x, w.x, acc[g]);
            acc[g] = fmaf(a.y, w.y, acc[g]);
            acc[g] = fmaf(a.z, w.z, acc[g]);
            acc[g] = fmaf(a.w, w.w, acc[g]);
        }
    }
#pragma unroll
    for (int g = 0; g < 16; g++) out[(size_t)(g0 + g) * 256 + t] = acc[g] + bv;
}

// ---------------------------------------------------------------------------
extern "C" void kernel_launch(void* const* d_in, const int* in_sizes, int n_in,
                              void* d_out, int out_size, void* d_ws, size_t ws_size,
                              hipStream_t stream) {
    const int* a_features = (const int*)d_in[0];
    const int* b_features = (const int*)d_in[1];
    const int* a_scopes   = (const int*)d_in[2];
    const float* emb      = (const float*)d_in[3];
    const float* W_in     = (const float*)d_in[4];
    const float* b_in     = (const float*)d_in[5];
    const float* W_self   = (const float*)d_in[6];
    const float* b_self   = (const float*)d_in[7];
    const float* W_neigh  = (const float*)d_in[8];
    const float* b_neigh  = (const float*)d_in[9];
    const float* W_out    = (const float*)d_in[10];
    const float* b_out    = (const float*)d_in[11];

    if (g_pool == nullptr) {
        fill_kernel<<<(out_size + 255) / 256, 256, 0, stream>>>(
            (float*)d_out, 77777.0f, out_size);
        return;
    }

    // ---- pool layout (halves); interleaved h buffers [hi256|lo256] ----
    f16* p = (f16*)g_pool;
    const size_t HB2 = (size_t)MP * HSTR;        // 153,616,384 halves / buffer
    f16* bufA = p;
    f16* bufB = p + HB2;
    f16* bufC = p + 2 * HB2;
    f16* xbuf = p + 3 * HB2;                     // [MP][64] interleaved
    f16* Winh = xbuf + (size_t)MP * XSTR;
    f16* Winl = Winh + HIDDIM * DCOL;
    f16* Wsh  = Winl + HIDDIM * DCOL;
    f16* Wsl  = Wsh + HIDDIM * HIDDIM;
    f16* Wnh  = Wsl + HIDDIM * HIDDIM;
    f16* Wnl  = Wnh + HIDDIM * HIDDIM;
    float* Gmean = (float*)(Wnl + HIDDIM * HIDDIM);        // [6000][256] fp32
    float* bsum  = Gmean + (size_t)NGRAPHS * HIDDIM;
    int* esrc = (int*)(bsum + HIDDIM);
    int* nxt  = esrc + 2 * NBONDS;
    int* head = nxt + 2 * NBONDS;

    constexpr int NPAD = MP - NATOMS;            // 32 pad rows

    // ---- setup (identical every launch) ----
    hipMemsetAsync(head, 0xFF, (size_t)MP * sizeof(int), stream);
    build_edges_kernel<<<(2 * NBONDS + 255) / 256, 256, 0, stream>>>(b_features, esrc, nxt, head);
    wsplit_kernel<<<(HIDDIM * DCOL + 255) / 256, 256, 0, stream>>>(W_in, Winh, Winl, HIDDIM * DCOL);
    wsplit_kernel<<<(HIDDIM * HIDDIM + 255) / 256, 256, 0, stream>>>(W_self, Wsh, Wsl, HIDDIM * HIDDIM);
    wsplit_kernel<<<(HIDDIM * HIDDIM + 255) / 256, 256, 0, stream>>>(W_neigh, Wnh, Wnl, HIDDIM * HIDDIM);
    bsum_kernel<<<1, HIDDIM, 0, stream>>>(b_self, b_neigh, bsum);

    // Zero padding rows (pool is persistent; keeps pad lanes deterministic).
    constexpr int PADH = NPAD * HSTR / 2;        // halves -> floats
    fill_kernel<<<(PADH + 255) / 256, 256, 0, stream>>>((float*)(bufA + (size_t)NATOMS * HSTR), 0.f, PADH);
    fill_kernel<<<(PADH + 255) / 256, 256, 0, stream>>>((float*)(bufB + (size_t)NATOMS * HSTR), 0.f, PADH);
    fill_kernel<<<(PADH + 255) / 256, 256, 0, stream>>>((float*)(bufC + (size_t)NATOMS * HSTR), 0.f, PADH);
    constexpr int PADX = NPAD * XSTR / 2;
    fill_kernel<<<(PADX + 255) / 256, 256, 0, stream>>>((float*)(xbuf + (size_t)NATOMS * XSTR), 0.f, PADX);

    // ---- embedding + input linear -> h (bufA) ----
    embed_kernel<<<(NATOMS * DCOL + 255) / 256, 256, 0, stream>>>(a_features, emb, xbuf);
    mfma_gemm<false, false, DCOL><<<MTILES128, 512, 0, stream>>>(
        xbuf, nullptr, Winh, Winl, nullptr, nullptr, b_in, bufA);

    // ---- 3 message-passing steps with rotating buffers ----
    f16* h  = bufA;
    f16* g  = bufB;
    f16* hn = bufC;
    for (int s = 0; s < NSTEPS; s++) {
        agg_kernel<<<NATOMS / 4, 256, 0, stream>>>(h, g, head, nxt, esrc);
        mfma_gemm<true, true, HIDDIM><<<MTILES128, 512, 0, stream>>>(
            h, g, Wsh, Wsl, Wnh, Wnl, bsum, hn);
        f16* old = h;
        h = hn; hn = g; g = old;
    }

    // ---- mean first (linearity), then tiny output linear ----
    readout_mean_kernel<<<NGRAPHS, 256, 0, stream>>>(h, a_scopes, Gmean);
    out_gemm_kernel<<<NGRAPHS / 16, 256, 0, stream>>>(Gmean, W_out, b_out, (float*)d_out);
}

// Round 4
// 1925.172 us; speedup vs baseline: 1.0614x; 1.0100x over previous
//
#include <hip/hip_runtime.h>

#define NATOMS 300000
#define NCOLS 8
#define VOCABSZ 4096
#define DCOL 32
#define HIDDIM 256
#define NBONDS 320000
#define NGRAPHS 6000
#define NSTEPS 3

constexpr int MP = 300032;             // atoms padded to multiple of 128
constexpr int MTILES128 = MP / 128;    // 2344 gemm blocks
constexpr int HSTR = 2 * HIDDIM;       // interleaved h row: [hi256|lo256]
constexpr int XSTR = 2 * DCOL;         // interleaved x row: [hi32|lo32]

typedef _Float16 f16;
typedef _Float16 f16x8 __attribute__((ext_vector_type(8)));
typedef float f32x4 __attribute__((ext_vector_type(4)));

constexpr float LO_SCALE = 2048.0f;      // 2^11: keeps lo parts fp16-normal
constexpr float INV_LO   = 1.0f / 2048.0f;

__device__ __forceinline__ void split2(float x, f16& h, f16& l) {
    h = (f16)x;
    l = (f16)((x - (float)h) * LO_SCALE);
}

// 16B-unit XOR swizzle (r10: measured ZERO bank conflicts). Involution in q.
__device__ __forceinline__ int swz(int row, int q) {
    return (row * 4 + (q ^ ((row >> 1) & 3))) * 8;
}

// Async global->LDS DMA, 16B per lane per wave-instruction.
__device__ __forceinline__ void dma16(const f16* g, f16* l) {
    __builtin_amdgcn_global_load_lds(
        (const __attribute__((address_space(1))) uint32_t*)g,
        (__attribute__((address_space(3))) uint32_t*)l, 16, 0, 0);
}

// ---------------------------------------------------------------------------
static void* g_pool = nullptr;
__attribute__((constructor)) static void alloc_pool() {
    void* p = nullptr;
    if (hipMalloc(&p, (size_t)1024 * 1024 * 1024) == hipSuccess) {
        hipMemset(p, 0, (size_t)1024 * 1024 * 1024);
        g_pool = p;
    }
}

// ---------------------------------------------------------------------------
__global__ void fill_kernel(float* out, float v, int n) {
    int i = blockIdx.x * blockDim.x + threadIdx.x;
    if (i < n) out[i] = v;
}

// ---------------------------------------------------------------------------
__global__ void build_edges_kernel(const int* __restrict__ bf, int* __restrict__ esrc,
                                   int* __restrict__ nxt, int* head) {
    int e = blockIdx.x * blockDim.x + threadIdx.x;
    if (e >= 2 * NBONDS) return;
    int src, dst;
    if (e < NBONDS) { src = bf[e * 3 + 0]; dst = bf[e * 3 + 1]; }
    else { int i = e - NBONDS; src = bf[i * 3 + 1]; dst = bf[i * 3 + 0]; }
    esrc[e] = src;
    nxt[e] = atomicExch(&head[dst], e);
}

// ---------------------------------------------------------------------------
__global__ void wsplit_kernel(const float* __restrict__ W, f16* __restrict__ Wh,
                              f16* __restrict__ Wl, int n) {
    int i = blockIdx.x * blockDim.x + threadIdx.x;
    if (i >= n) return;
    split2(W[i], Wh[i], Wl[i]);
}

__global__ void bsum_kernel(const float* __restrict__ a, const float* __restrict__ b,
                            float* __restrict__ o) {
    int i = threadIdx.x;
    o[i] = a[i] + b[i];
}

// ---------------------------------------------------------------------------
// Embedding -> interleaved x rows [hi32|lo32].
__global__ void embed_kernel(const int* __restrict__ af, const float* __restrict__ emb,
                             f16* __restrict__ x) {
    int gid = blockIdx.x * blockDim.x + threadIdx.x;
    int i = gid >> 5, k = gid & 31;
    if (i >= NATOMS) return;
    float s = 0.0f;
#pragma unroll
    for (int c = 0; c < NCOLS; c++) {
        int v = af[i * NCOLS + c];
        int idx = v & (VOCABSZ - 1);
        if (v >= 999999999) idx = 0;
        s += emb[((size_t)c * VOCABSZ + idx) * DCOL + k];
    }
    f16 hi, lo;
    split2(s, hi, lo);
    x[(size_t)i * XSTR + k] = hi;
    x[(size_t)i * XSTR + DCOL + k] = lo;
}

// ---------------------------------------------------------------------------
// Aggregation over interleaved rows (unchanged, proven).
__global__ void agg_kernel(const f16* __restrict__ H, f16* __restrict__ G,
                           const int* __restrict__ head, const int* __restrict__ nxt,
                           const int* __restrict__ esrc) {
    int wid = (blockIdx.x * blockDim.x + threadIdx.x) >> 6;
    int lane = threadIdx.x & 63;
    if (wid >= NATOMS) return;
    float a0 = 0.f, a1 = 0.f, a2 = 0.f, a3 = 0.f,
          a4 = 0.f, a5 = 0.f, a6 = 0.f, a7 = 0.f;
    int e = head[wid];
    while (e >= 0) {
        int src = esrc[e];
        const f16x8 v = *(const f16x8*)(H + (size_t)src * HSTR + lane * 8);
        a0 += (float)v[0]; a1 += (float)v[1]; a2 += (float)v[2]; a3 += (float)v[3];
        a4 += (float)v[4]; a5 += (float)v[5]; a6 += (float)v[6]; a7 += (float)v[7];
        e = nxt[e];
    }
    const bool isLo = lane >= 32;
    if (isLo) {
        a0 *= INV_LO; a1 *= INV_LO; a2 *= INV_LO; a3 *= INV_LO;
        a4 *= INV_LO; a5 *= INV_LO; a6 *= INV_LO; a7 *= INV_LO;
    }
    float s0 = a0 + __shfl_xor(a0, 32, 64);
    float s1 = a1 + __shfl_xor(a1, 32, 64);
    float s2 = a2 + __shfl_xor(a2, 32, 64);
    float s3 = a3 + __shfl_xor(a3, 32, 64);
    float s4 = a4 + __shfl_xor(a4, 32, 64);
    float s5 = a5 + __shfl_xor(a5, 32, 64);
    float s6 = a6 + __shfl_xor(a6, 32, 64);
    float s7 = a7 + __shfl_xor(a7, 32, 64);
    f16x8 o;
#define EMIT(J, S)                                                    \
    {                                                                 \
        const f16 hv = (f16)(S);                                      \
        o[J] = isLo ? (f16)(((S) - (float)hv) * LO_SCALE) : hv;       \
    }
    EMIT(0, s0) EMIT(1, s1) EMIT(2, s2) EMIT(3, s3)
    EMIT(4, s4) EMIT(5, s5) EMIT(6, s6) EMIT(7, s7)
#undef EMIT
    *(f16x8*)(G + (size_t)wid * HSTR + lane * 8) = o;
}

// ---------------------------------------------------------------------------
// MFMA GEMM v5: R3's verified compute + staging, with prefetch depth 2.
// Theory: per-CU HBM share is ~10.2 B/cy, so a stage's 16KB A-tile needs
// ~1600cy of HBM service ~= the whole compute phase (1860cy). Depth-1
// prefetch (R1/R3) leaves ZERO slack -> every stage stalls in the drain
// (measured ~5400cy/stage vs 1863 ideal, MfmaUtil pinned at ~31% across 3
// structures). Fix: THREE 48KB LDS buffers (144KB, still 1 block/CU),
// prologue issues stages 0+1, loop issues stage s+2 after the barrier, and
// the barrier is raw s_barrier with COUNTED vmcnt(6): allow the 6 newest
// VMEM ops (= DMA(s+1)), require DMA(s) retired. vmcnt(0) only at the final
// stage. Every DMA now has ~2 compute stages (~3800cy) of slack vs ~1600cy
// service. Visibility protocol (own-vmcnt + s_barrier) validated in R1.
// Buffer-reuse safety: DMA(s+2) writes buf (s-1)%3, whose readers all
// retired before the stage-s barrier (lgkmcnt(0) in the wait).
template <bool HAS_A2, bool RELU, int K>
__global__ __launch_bounds__(512, 2) void mfma_gemm(
    const f16* __restrict__ A1, const f16* __restrict__ A2,
    const f16* __restrict__ B1h, const f16* __restrict__ B1l,
    const f16* __restrict__ B2h, const f16* __restrict__ B2l,
    const float* __restrict__ bias, f16* __restrict__ C) {
    // per-stage buffer (halves): [A-hi 128x32][A-lo][B-hi 256x32][B-lo]
    constexpr int OAH = 0, OAL = 4096, OBH = 8192, OBL = 16384, BUFH = 24576;
    __shared__ __align__(16) f16 lds[3 * BUFH];   // 144 KB

    const int t = threadIdx.x;
    const int m0 = blockIdx.x * 128;
    const int lane = t & 63;
    const int wid = t >> 6;        // 0..7
    const int wr = wid >> 2;       // 0..1 : row  half (64 rows)
    const int wc = wid & 3;        // 0..3 : col quarter (64 cols)
    const int quad = lane >> 4;
    const int l16 = lane & 15;

    // staging geometry: wave w stages rows [w*16, w*16+16), lane -> (row, q)
    const int ra_ = wid * 16 + (lane >> 2);
    const int qs_ = (lane & 3) ^ ((ra_ >> 1) & 3);   // inverse-swizzled quad
    const int ko_ = qs_ * 8;

    f32x4 acch[4][4], accl[4][4];   // [mt][nt]
#pragma unroll
    for (int a = 0; a < 4; a++)
#pragma unroll
        for (int b = 0; b < 4; b++) {
            acch[a][b] = (f32x4){0.f, 0.f, 0.f, 0.f};
            accl[a][b] = (f32x4){0.f, 0.f, 0.f, 0.f};
        }

    constexpr int NMAT = HAS_A2 ? 2 : 1;
    constexpr int NST = (K / 32) * NMAT;

#define ISSUE_STAGE(S, BUF)                                                    \
    {                                                                          \
        const int mat_ = HAS_A2 ? ((S) & 1) : 0;                               \
        const int kb_ = (HAS_A2 ? ((S) >> 1) : (S)) * 32;                      \
        const f16* A_ = (mat_ == 0) ? A1 : A2;                                 \
        const f16* Bh_ = (mat_ == 0) ? B1h : B2h;                              \
        const f16* Bl_ = (mat_ == 0) ? B1l : B2l;                              \
        f16* const dst_ = lds + (BUF) * BUFH + wid * 512;                      \
        const size_t arow_ = (size_t)(m0 + ra_) * (2 * K) + kb_ + ko_;         \
        dma16(A_ + arow_, dst_ + OAH);                                         \
        dma16(A_ + arow_ + K, dst_ + OAL);                                     \
        const size_t brow_ = (size_t)ra_ * K + kb_ + ko_;                      \
        dma16(Bh_ + brow_, dst_ + OBH);                                        \
        dma16(Bh_ + brow_ + (size_t)128 * K, dst_ + OBH + 4096);               \
        dma16(Bl_ + brow_, dst_ + OBL);                                        \
        dma16(Bl_ + brow_ + (size_t)128 * K, dst_ + OBL + 4096);               \
    }

#define COMPUTE_STAGE(BUF)                                                     \
    {                                                                          \
        const f16* cb = lds + (BUF) * BUFH;                                    \
        const f16* sAh = cb + OAH;                                             \
        const f16* sAl = cb + OAL;                                             \
        const f16* sBh = cb + OBH;                                             \
        const f16* sBl = cb + OBL;                                             \
        f16x8 fah[4], fal[4];                                                  \
        _Pragma("unroll")                                                      \
        for (int mt = 0; mt < 4; mt++) {                                       \
            const int src = swz(wr * 64 + mt * 16 + l16, quad);                \
            fah[mt] = *(const f16x8*)(sAh + src);                              \
            fal[mt] = *(const f16x8*)(sAl + src);                              \
        }                                                                      \
        _Pragma("unroll")                                                      \
        for (int nt = 0; nt < 4; nt++) {                                       \
            const int src = swz(wc * 64 + nt * 16 + l16, quad);                \
            const f16x8 bh = *(const f16x8*)(sBh + src);                       \
            const f16x8 bl = *(const f16x8*)(sBl + src);                       \
            _Pragma("unroll")                                                  \
            for (int mt = 0; mt < 4; mt++) {                                   \
                acch[mt][nt] = __builtin_amdgcn_mfma_f32_16x16x32_f16(         \
                    fah[mt], bh, acch[mt][nt], 0, 0, 0);                       \
                accl[mt][nt] = __builtin_amdgcn_mfma_f32_16x16x32_f16(         \
                    fah[mt], bl, accl[mt][nt], 0, 0, 0);                       \
                accl[mt][nt] = __builtin_amdgcn_mfma_f32_16x16x32_f16(         \
                    fal[mt], bh, accl[mt][nt], 0, 0, 0);                       \
            }                                                                  \
        }                                                                      \
    }

    // ---- prologue: depth-2 prefetch into bufs 0 and 1 ----
    ISSUE_STAGE(0, 0);
    asm volatile("" ::: "memory");
    if (NST > 1) ISSUE_STAGE(1, 1);

    int buf = 0;   // s % 3
    for (int s = 0; s < NST - 1; s++) {
        // require DMA(s) retired; allow the 6 newest (= DMA(s+1)) in flight.
        asm volatile("s_waitcnt vmcnt(6) lgkmcnt(0)" ::: "memory");
        __builtin_amdgcn_s_barrier();
        __builtin_amdgcn_sched_barrier(0);
        if (s + 2 < NST) {
            int nb = buf + 2; if (nb >= 3) nb -= 3;
            ISSUE_STAGE(s + 2, nb);
        }
        COMPUTE_STAGE(buf);
        buf = (buf == 2) ? 0 : buf + 1;
    }
    // ---- final stage: nothing younger allowed ----
    asm volatile("s_waitcnt vmcnt(0) lgkmcnt(0)" ::: "memory");
    __builtin_amdgcn_s_barrier();
    __builtin_amdgcn_sched_barrier(0);
    COMPUTE_STAGE(buf);
#undef ISSUE_STAGE
#undef COMPUTE_STAGE

#pragma unroll
    for (int mt = 0; mt < 4; mt++) {
#pragma unroll
        for (int nt = 0; nt < 4; nt++) {
            const int col = wc * 64 + nt * 16 + l16;
            const float bv = bias[col];
#pragma unroll
            for (int r = 0; r < 4; r++) {
                const int row = m0 + wr * 64 + mt * 16 + quad * 4 + r;
                float v = acch[mt][nt][r] + accl[mt][nt][r] * INV_LO + bv;
                if (RELU) v = fmaxf(v, 0.f);
                f16 hi, lo;
                split2(v, hi, lo);
                C[(size_t)row * HSTR + col] = hi;
                C[(size_t)row * HSTR + HIDDIM + col] = lo;
            }
        }
    }
}

// ---------------------------------------------------------------------------
// Segment-mean of interleaved final h -> G[6000][256] fp32.
__global__ void readout_mean_kernel(const f16* __restrict__ H,
                                    const int* __restrict__ scopes, float* __restrict__ G) {
    int g = blockIdx.x;
    int n = threadIdx.x;
    int start = scopes[g * 2 + 0];
    int len = scopes[g * 2 + 1];
    float s = 0.f;
    for (int j = 0; j < len; j++) {
        const f16* row = H + (size_t)(start + j) * HSTR;
        s += (float)row[n] + (float)row[HIDDIM + n] * INV_LO;
    }
    int d = len > 1 ? len : 1;
    G[(size_t)g * HIDDIM + n] = s / (float)d;
}

// ---------------------------------------------------------------------------
// Tiny fp32 GEMM: out[g][n] = G[g][:] . W_out[n][:] + b_out[n], g<6000.
__global__ __launch_bounds__(256) void out_gemm_kernel(
    const float* __restrict__ G, const float* __restrict__ W,
    const float* __restrict__ bias, float* __restrict__ out) {
    __shared__ float sG[16 * 256];
    const int g0 = blockIdx.x * 16;
    const int t = threadIdx.x;
#pragma unroll
    for (int i = 0; i < 16; i++) sG[i * 256 + t] = G[(size_t)(g0 + i) * 256 + t];
    __syncthreads();
    const float bv = bias[t];
    const float* wrow = W + (size_t)t * 256;   // W[n][k] row-major
    float acc[16];
#pragma unroll
    for (int g = 0; g < 16; g++) acc[g] = 0.f;
    for (int k = 0; k < 256; k += 4) {
        const float4 w = *(const float4*)(wrow + k);
#pragma unroll
        for (int g = 0; g < 16; g++) {
            const float4 a = *(const float4*)(sG + g * 256 + k);   // broadcast
            acc[g] = fmaf(a.x, w.x, acc[g]);
            acc[g] = fmaf(a.y, w.y, acc[g]);
            acc[g] = fmaf(a.z, w.z, acc[g]);
            acc[g] = fmaf(a.w, w.w, acc[g]);
        }
    }
#pragma unroll
    for (int g = 0; g < 16; g++) out[(size_t)(g0 + g) * 256 + t] = acc[g] + bv;
}

// ---------------------------------------------------------------------------
extern "C" void kernel_launch(void* const* d_in, const int* in_sizes, int n_in,
                              void* d_out, int out_size, void* d_ws, size_t ws_size,
                              hipStream_t stream) {
    const int* a_features = (const int*)d_in[0];
    const int* b_features = (const int*)d_in[1];
    const int* a_scopes   = (const int*)d_in[2];
    const float* emb      = (const float*)d_in[3];
    const float* W_in     = (const float*)d_in[4];
    const float* b_in     = (const float*)d_in[5];
    const float* W_self   = (const float*)d_in[6];
    const float* b_self   = (const float*)d_in[7];
    const float* W_neigh  = (const float*)d_in[8];
    const float* b_neigh  = (const float*)d_in[9];
    const float* W_out    = (const float*)d_in[10];
    const float* b_out    = (const float*)d_in[11];

    if (g_pool == nullptr) {
        fill_kernel<<<(out_size + 255) / 256, 256, 0, stream>>>(
            (float*)d_out, 77777.0f, out_size);
        return;
    }

    // ---- pool layout (halves); interleaved h buffers [hi256|lo256] ----
    f16* p = (f16*)g_pool;
    const size_t HB2 = (size_t)MP * HSTR;        // 153,616,384 halves / buffer
    f16* bufA = p;
    f16* bufB = p + HB2;
    f16* bufC = p + 2 * HB2;
    f16* xbuf = p + 3 * HB2;                     // [MP][64] interleaved
    f16* Winh = xbuf + (size_t)MP * XSTR;
    f16* Winl = Winh + HIDDIM * DCOL;
    f16* Wsh  = Winl + HIDDIM * DCOL;
    f16* Wsl  = Wsh + HIDDIM * HIDDIM;
    f16* Wnh  = Wsl + HIDDIM * HIDDIM;
    f16* Wnl  = Wnh + HIDDIM * HIDDIM;
    float* Gmean = (float*)(Wnl + HIDDIM * HIDDIM);        // [6000][256] fp32
    float* bsum  = Gmean + (size_t)NGRAPHS * HIDDIM;
    int* esrc = (int*)(bsum + HIDDIM);
    int* nxt  = esrc + 2 * NBONDS;
    int* head = nxt + 2 * NBONDS;

    constexpr int NPAD = MP - NATOMS;            // 32 pad rows

    // ---- setup (identical every launch) ----
    hipMemsetAsync(head, 0xFF, (size_t)MP * sizeof(int), stream);
    build_edges_kernel<<<(2 * NBONDS + 255) / 256, 256, 0, stream>>>(b_features, esrc, nxt, head);
    wsplit_kernel<<<(HIDDIM * DCOL + 255) / 256, 256, 0, stream>>>(W_in, Winh, Winl, HIDDIM * DCOL);
    wsplit_kernel<<<(HIDDIM * HIDDIM + 255) / 256, 256, 0, stream>>>(W_self, Wsh, Wsl, HIDDIM * HIDDIM);
    wsplit_kernel<<<(HIDDIM * HIDDIM + 255) / 256, 256, 0, stream>>>(W_neigh, Wnh, Wnl, HIDDIM * HIDDIM);
    bsum_kernel<<<1, HIDDIM, 0, stream>>>(b_self, b_neigh, bsum);

    // Zero padding rows (pool is persistent; keeps pad lanes deterministic).
    constexpr int PADH = NPAD * HSTR / 2;        // halves -> floats
    fill_kernel<<<(PADH + 255) / 256, 256, 0, stream>>>((float*)(bufA + (size_t)NATOMS * HSTR), 0.f, PADH);
    fill_kernel<<<(PADH + 255) / 256, 256, 0, stream>>>((float*)(bufB + (size_t)NATOMS * HSTR), 0.f, PADH);
    fill_kernel<<<(PADH + 255) / 256, 256, 0, stream>>>((float*)(bufC + (size_t)NATOMS * HSTR), 0.f, PADH);
    constexpr int PADX = NPAD * XSTR / 2;
    fill_kernel<<<(PADX + 255) / 256, 256, 0, stream>>>((float*)(xbuf + (size_t)NATOMS * XSTR), 0.f, PADX);

    // ---- embedding + input linear -> h (bufA) ----
    embed_kernel<<<(NATOMS * DCOL + 255) / 256, 256, 0, stream>>>(a_features, emb, xbuf);
    mfma_gemm<false, false, DCOL><<<MTILES128, 512, 0, stream>>>(
        xbuf, nullptr, Winh, Winl, nullptr, nullptr, b_in, bufA);

    // ---- 3 message-passing steps with rotating buffers ----
    f16* h  = bufA;
    f16* g  = bufB;
    f16* hn = bufC;
    for (int s = 0; s < NSTEPS; s++) {
        agg_kernel<<<NATOMS / 4, 256, 0, stream>>>(h, g, head, nxt, esrc);
        mfma_gemm<true, true, HIDDIM><<<MTILES128, 512, 0, stream>>>(
            h, g, Wsh, Wsl, Wnh, Wnl, bsum, hn);
        f16* old = h;
        h = hn; hn = g; g = old;
    }

    // ---- mean first (linearity), then tiny output linear ----
    readout_mean_kernel<<<NGRAPHS, 256, 0, stream>>>(h, a_scopes, Gmean);
    out_gemm_kernel<<<NGRAPHS / 16, 256, 0, stream>>>(Gmean, W_out, b_out, (float*)d_out);
}

// Round 5
// 1923.388 us; speedup vs baseline: 1.0624x; 1.0009x over previous
//
#include <hip/hip_runtime.h>

#define NATOMS 300000
#define NCOLS 8
#define VOCABSZ 4096
#define DCOL 32
#define HIDDIM 256
#define NBONDS 320000
#define NGRAPHS 6000
#define NSTEPS 3

constexpr int MP = 300032;             // atoms padded to multiple of 128
constexpr int MTILES128 = MP / 128;    // 2344 gemm blocks
constexpr int HSTR = 2 * HIDDIM;       // interleaved h row: [hi256|lo256]
constexpr int XSTR = 2 * DCOL;         // interleaved x row: [hi32|lo32]

typedef _Float16 f16;
typedef _Float16 f16x8 __attribute__((ext_vector_type(8)));
typedef float f32x4 __attribute__((ext_vector_type(4)));

constexpr float LO_SCALE = 2048.0f;      // 2^11: keeps lo parts fp16-normal
constexpr float INV_LO   = 1.0f / 2048.0f;

__device__ __forceinline__ void split2(float x, f16& h, f16& l) {
    h = (f16)x;
    l = (f16)((x - (float)h) * LO_SCALE);
}

// 16B-unit XOR swizzle (r10: measured ZERO bank conflicts). Involution in q.
__device__ __forceinline__ int swz(int row, int q) {
    return (row * 4 + (q ^ ((row >> 1) & 3))) * 8;
}

// Async global->LDS DMA, 16B per lane per wave-instruction.
__device__ __forceinline__ void dma16(const f16* g, f16* l) {
    __builtin_amdgcn_global_load_lds(
        (const __attribute__((address_space(1))) uint32_t*)g,
        (__attribute__((address_space(3))) uint32_t*)l, 16, 0, 0);
}

// ---------------------------------------------------------------------------
static void* g_pool = nullptr;
__attribute__((constructor)) static void alloc_pool() {
    void* p = nullptr;
    if (hipMalloc(&p, (size_t)1024 * 1024 * 1024) == hipSuccess) {
        hipMemset(p, 0, (size_t)1024 * 1024 * 1024);
        g_pool = p;
    }
}

// ---------------------------------------------------------------------------
__global__ void fill_kernel(float* out, float v, int n) {
    int i = blockIdx.x * blockDim.x + threadIdx.x;
    if (i < n) out[i] = v;
}

// ---------------------------------------------------------------------------
__global__ void build_edges_kernel(const int* __restrict__ bf, int* __restrict__ esrc,
                                   int* __restrict__ nxt, int* head) {
    int e = blockIdx.x * blockDim.x + threadIdx.x;
    if (e >= 2 * NBONDS) return;
    int src, dst;
    if (e < NBONDS) { src = bf[e * 3 + 0]; dst = bf[e * 3 + 1]; }
    else { int i = e - NBONDS; src = bf[i * 3 + 1]; dst = bf[i * 3 + 0]; }
    esrc[e] = src;
    nxt[e] = atomicExch(&head[dst], e);
}

// ---------------------------------------------------------------------------
__global__ void wsplit_kernel(const float* __restrict__ W, f16* __restrict__ Wh,
                              f16* __restrict__ Wl, int n) {
    int i = blockIdx.x * blockDim.x + threadIdx.x;
    if (i >= n) return;
    split2(W[i], Wh[i], Wl[i]);
}

__global__ void bsum_kernel(const float* __restrict__ a, const float* __restrict__ b,
                            float* __restrict__ o) {
    int i = threadIdx.x;
    o[i] = a[i] + b[i];
}

// ---------------------------------------------------------------------------
// Embedding -> interleaved x rows [hi32|lo32].
__global__ void embed_kernel(const int* __restrict__ af, const float* __restrict__ emb,
                             f16* __restrict__ x) {
    int gid = blockIdx.x * blockDim.x + threadIdx.x;
    int i = gid >> 5, k = gid & 31;
    if (i >= NATOMS) return;
    float s = 0.0f;
#pragma unroll
    for (int c = 0; c < NCOLS; c++) {
        int v = af[i * NCOLS + c];
        int idx = v & (VOCABSZ - 1);
        if (v >= 999999999) idx = 0;
        s += emb[((size_t)c * VOCABSZ + idx) * DCOL + k];
    }
    f16 hi, lo;
    split2(s, hi, lo);
    x[(size_t)i * XSTR + k] = hi;
    x[(size_t)i * XSTR + DCOL + k] = lo;
}

// ---------------------------------------------------------------------------
// Aggregation over interleaved rows (unchanged, proven).
__global__ void agg_kernel(const f16* __restrict__ H, f16* __restrict__ G,
                           const int* __restrict__ head, const int* __restrict__ nxt,
                           const int* __restrict__ esrc) {
    int wid = (blockIdx.x * blockDim.x + threadIdx.x) >> 6;
    int lane = threadIdx.x & 63;
    if (wid >= NATOMS) return;
    float a0 = 0.f, a1 = 0.f, a2 = 0.f, a3 = 0.f,
          a4 = 0.f, a5 = 0.f, a6 = 0.f, a7 = 0.f;
    int e = head[wid];
    while (e >= 0) {
        int src = esrc[e];
        const f16x8 v = *(const f16x8*)(H + (size_t)src * HSTR + lane * 8);
        a0 += (float)v[0]; a1 += (float)v[1]; a2 += (float)v[2]; a3 += (float)v[3];
        a4 += (float)v[4]; a5 += (float)v[5]; a6 += (float)v[6]; a7 += (float)v[7];
        e = nxt[e];
    }
    const bool isLo = lane >= 32;
    if (isLo) {
        a0 *= INV_LO; a1 *= INV_LO; a2 *= INV_LO; a3 *= INV_LO;
        a4 *= INV_LO; a5 *= INV_LO; a6 *= INV_LO; a7 *= INV_LO;
    }
    float s0 = a0 + __shfl_xor(a0, 32, 64);
    float s1 = a1 + __shfl_xor(a1, 32, 64);
    float s2 = a2 + __shfl_xor(a2, 32, 64);
    float s3 = a3 + __shfl_xor(a3, 32, 64);
    float s4 = a4 + __shfl_xor(a4, 32, 64);
    float s5 = a5 + __shfl_xor(a5, 32, 64);
    float s6 = a6 + __shfl_xor(a6, 32, 64);
    float s7 = a7 + __shfl_xor(a7, 32, 64);
    f16x8 o;
#define EMIT(J, S)                                                    \
    {                                                                 \
        const f16 hv = (f16)(S);                                      \
        o[J] = isLo ? (f16)(((S) - (float)hv) * LO_SCALE) : hv;       \
    }
    EMIT(0, s0) EMIT(1, s1) EMIT(2, s2) EMIT(3, s3)
    EMIT(4, s4) EMIT(5, s5) EMIT(6, s6) EMIT(7, s7)
#undef EMIT
    *(f16x8*)(G + (size_t)wid * HSTR + lane * 8) = o;
}

// ---------------------------------------------------------------------------
// MFMA GEMM v6: R4's staging (depth-2 DMA, 3x48KB bufs, counted vmcnt) with
// the compute split into 3 PHASES per stage (T3+T5 port). R4 evidence: stage
// time 5160cy = MFMA 1862 + LDS 1966 + misc SERIAL — all 8 waves are
// barrier-aligned, so they all ds_read together (MFMA idle) then all MFMA
// together (LDS idle). Fix: phase the stage as
//   A: read {fah x4, bh x4} -> 16 MFMA acch += fah*bh
//   B: read {bl x4}         -> 16 MFMA accl += fah*bl   (fah reused in reg)
//   C: read {fal x4}        -> 16 MFMA accl += fal*bh   (bh reused in reg)
// delimited by sched_barrier(0) (compiler may not merge phases back), MFMA
// clusters wrapped in s_setprio(1/0) (waves in MFMA preempt waves issuing
// reads). NO intra-stage s_barrier: 3 full buffers make them unnecessary,
// and wave drift across phases is the point (anti-phase pipe overlap).
// Stage boundary protocol unchanged from R4 (vmcnt(6), s_barrier, issue
// DMA(s+2)); rule-18 sched_barrier(0) follows the inline lgkmcnt.
template <bool HAS_A2, bool RELU, int K>
__global__ __launch_bounds__(512, 2) void mfma_gemm(
    const f16* __restrict__ A1, const f16* __restrict__ A2,
    const f16* __restrict__ B1h, const f16* __restrict__ B1l,
    const f16* __restrict__ B2h, const f16* __restrict__ B2l,
    const float* __restrict__ bias, f16* __restrict__ C) {
    // per-stage buffer (halves): [A-hi 128x32][A-lo][B-hi 256x32][B-lo]
    constexpr int OAH = 0, OAL = 4096, OBH = 8192, OBL = 16384, BUFH = 24576;
    __shared__ __align__(16) f16 lds[3 * BUFH];   // 144 KB

    const int t = threadIdx.x;
    const int m0 = blockIdx.x * 128;
    const int lane = t & 63;
    const int wid = t >> 6;        // 0..7
    const int wr = wid >> 2;       // 0..1 : row  half (64 rows)
    const int wc = wid & 3;        // 0..3 : col quarter (64 cols)
    const int quad = lane >> 4;
    const int l16 = lane & 15;

    // staging geometry: wave w stages rows [w*16, w*16+16), lane -> (row, q)
    const int ra_ = wid * 16 + (lane >> 2);
    const int qs_ = (lane & 3) ^ ((ra_ >> 1) & 3);   // inverse-swizzled quad
    const int ko_ = qs_ * 8;

    f32x4 acch[4][4], accl[4][4];   // [mt][nt]
#pragma unroll
    for (int a = 0; a < 4; a++)
#pragma unroll
        for (int b = 0; b < 4; b++) {
            acch[a][b] = (f32x4){0.f, 0.f, 0.f, 0.f};
            accl[a][b] = (f32x4){0.f, 0.f, 0.f, 0.f};
        }

    constexpr int NMAT = HAS_A2 ? 2 : 1;
    constexpr int NST = (K / 32) * NMAT;

#define ISSUE_STAGE(S, BUF)                                                    \
    {                                                                          \
        const int mat_ = HAS_A2 ? ((S) & 1) : 0;                               \
        const int kb_ = (HAS_A2 ? ((S) >> 1) : (S)) * 32;                      \
        const f16* A_ = (mat_ == 0) ? A1 : A2;                                 \
        const f16* Bh_ = (mat_ == 0) ? B1h : B2h;                              \
        const f16* Bl_ = (mat_ == 0) ? B1l : B2l;                              \
        f16* const dst_ = lds + (BUF) * BUFH + wid * 512;                      \
        const size_t arow_ = (size_t)(m0 + ra_) * (2 * K) + kb_ + ko_;         \
        dma16(A_ + arow_, dst_ + OAH);                                         \
        dma16(A_ + arow_ + K, dst_ + OAL);                                     \
        const size_t brow_ = (size_t)ra_ * K + kb_ + ko_;                      \
        dma16(Bh_ + brow_, dst_ + OBH);                                        \
        dma16(Bh_ + brow_ + (size_t)128 * K, dst_ + OBH + 4096);               \
        dma16(Bl_ + brow_, dst_ + OBL);                                        \
        dma16(Bl_ + brow_ + (size_t)128 * K, dst_ + OBL + 4096);               \
    }

    // 3-phase compute over buffer BUF (see header comment).
#define COMPUTE_STAGE(BUF)                                                     \
    {                                                                          \
        const f16* cb = lds + (BUF) * BUFH;                                    \
        const f16* sAh = cb + OAH;                                             \
        const f16* sAl = cb + OAL;                                             \
        const f16* sBh = cb + OBH;                                             \
        const f16* sBl = cb + OBL;                                             \
        f16x8 fah[4], fal[4], bh[4], bl[4];                                    \
        /* ---- phase A: fah+bh reads, acch pass ---- */                       \
        _Pragma("unroll")                                                      \
        for (int mt = 0; mt < 4; mt++)                                         \
            fah[mt] = *(const f16x8*)(sAh + swz(wr * 64 + mt * 16 + l16, quad)); \
        _Pragma("unroll")                                                      \
        for (int nt = 0; nt < 4; nt++)                                         \
            bh[nt] = *(const f16x8*)(sBh + swz(wc * 64 + nt * 16 + l16, quad)); \
        __builtin_amdgcn_s_setprio(1);                                         \
        _Pragma("unroll")                                                      \
        for (int nt = 0; nt < 4; nt++)                                         \
            _Pragma("unroll")                                                  \
            for (int mt = 0; mt < 4; mt++)                                     \
                acch[mt][nt] = __builtin_amdgcn_mfma_f32_16x16x32_f16(         \
                    fah[mt], bh[nt], acch[mt][nt], 0, 0, 0);                   \
        __builtin_amdgcn_s_setprio(0);                                         \
        __builtin_amdgcn_sched_barrier(0);                                     \
        /* ---- phase B: bl reads, accl += fah*bl ---- */                      \
        _Pragma("unroll")                                                      \
        for (int nt = 0; nt < 4; nt++)                                         \
            bl[nt] = *(const f16x8*)(sBl + swz(wc * 64 + nt * 16 + l16, quad)); \
        __builtin_amdgcn_s_setprio(1);                                         \
        _Pragma("unroll")                                                      \
        for (int nt = 0; nt < 4; nt++)                                         \
            _Pragma("unroll")                                                  \
            for (int mt = 0; mt < 4; mt++)                                     \
                accl[mt][nt] = __builtin_amdgcn_mfma_f32_16x16x32_f16(         \
                    fah[mt], bl[nt], accl[mt][nt], 0, 0, 0);                   \
        __builtin_amdgcn_s_setprio(0);                                         \
        __builtin_amdgcn_sched_barrier(0);                                     \
        /* ---- phase C: fal reads, accl += fal*bh ---- */                     \
        _Pragma("unroll")                                                      \
        for (int mt = 0; mt < 4; mt++)                                         \
            fal[mt] = *(const f16x8*)(sAl + swz(wr * 64 + mt * 16 + l16, quad)); \
        __builtin_amdgcn_s_setprio(1);                                         \
        _Pragma("unroll")                                                      \
        for (int nt = 0; nt < 4; nt++)                                         \
            _Pragma("unroll")                                                  \
            for (int mt = 0; mt < 4; mt++)                                     \
                accl[mt][nt] = __builtin_amdgcn_mfma_f32_16x16x32_f16(         \
                    fal[mt], bh[nt], accl[mt][nt], 0, 0, 0);                   \
        __builtin_amdgcn_s_setprio(0);                                         \
    }

    // ---- prologue: depth-2 prefetch into bufs 0 and 1 ----
    ISSUE_STAGE(0, 0);
    asm volatile("" ::: "memory");
    if (NST > 1) ISSUE_STAGE(1, 1);

    int buf = 0;   // s % 3
    for (int s = 0; s < NST - 1; s++) {
        // require DMA(s) retired; allow the 6 newest (= DMA(s+1)) in flight.
        asm volatile("s_waitcnt vmcnt(6) lgkmcnt(0)" ::: "memory");
        __builtin_amdgcn_s_barrier();
        __builtin_amdgcn_sched_barrier(0);
        if (s + 2 < NST) {
            int nb = buf + 2; if (nb >= 3) nb -= 3;
            ISSUE_STAGE(s + 2, nb);
        }
        __builtin_amdgcn_sched_barrier(0);
        COMPUTE_STAGE(buf);
        buf = (buf == 2) ? 0 : buf + 1;
    }
    // ---- final stage: nothing younger allowed ----
    asm volatile("s_waitcnt vmcnt(0) lgkmcnt(0)" ::: "memory");
    __builtin_amdgcn_s_barrier();
    __builtin_amdgcn_sched_barrier(0);
    COMPUTE_STAGE(buf);
#undef ISSUE_STAGE
#undef COMPUTE_STAGE

#pragma unroll
    for (int mt = 0; mt < 4; mt++) {
#pragma unroll
        for (int nt = 0; nt < 4; nt++) {
            const int col = wc * 64 + nt * 16 + l16;
            const float bv = bias[col];
#pragma unroll
            for (int r = 0; r < 4; r++) {
                const int row = m0 + wr * 64 + mt * 16 + quad * 4 + r;
                float v = acch[mt][nt][r] + accl[mt][nt][r] * INV_LO + bv;
                if (RELU) v = fmaxf(v, 0.f);
                f16 hi, lo;
                split2(v, hi, lo);
                C[(size_t)row * HSTR + col] = hi;
                C[(size_t)row * HSTR + HIDDIM + col] = lo;
            }
        }
    }
}

// ---------------------------------------------------------------------------
// Segment-mean of interleaved final h -> G[6000][256] fp32.
__global__ void readout_mean_kernel(const f16* __restrict__ H,
                                    const int* __restrict__ scopes, float* __restrict__ G) {
    int g = blockIdx.x;
    int n = threadIdx.x;
    int start = scopes[g * 2 + 0];
    int len = scopes[g * 2 + 1];
    float s = 0.f;
    for (int j = 0; j < len; j++) {
        const f16* row = H + (size_t)(start + j) * HSTR;
        s += (float)row[n] + (float)row[HIDDIM + n] * INV_LO;
    }
    int d = len > 1 ? len : 1;
    G[(size_t)g * HIDDIM + n] = s / (float)d;
}

// ---------------------------------------------------------------------------
// Tiny fp32 GEMM: out[g][n] = G[g][:] . W_out[n][:] + b_out[n], g<6000.
__global__ __launch_bounds__(256) void out_gemm_kernel(
    const float* __restrict__ G, const float* __restrict__ W,
    const float* __restrict__ bias, float* __restrict__ out) {
    __shared__ float sG[16 * 256];
    const int g0 = blockIdx.x * 16;
    const int t = threadIdx.x;
#pragma unroll
    for (int i = 0; i < 16; i++) sG[i * 256 + t] = G[(size_t)(g0 + i) * 256 + t];
    __syncthreads();
    const float bv = bias[t];
    const float* wrow = W + (size_t)t * 256;   // W[n][k] row-major
    float acc[16];
#pragma unroll
    for (int g = 0; g < 16; g++) acc[g] = 0.f;
    for (int k = 0; k < 256; k += 4) {
        const float4 w = *(const float4*)(wrow + k);
#pragma unroll
        for (int g = 0; g < 16; g++) {
            const float4 a = *(const float4*)(sG + g * 256 + k);   // broadcast
            acc[g] = fmaf(a.x, w.x, acc[g]);
            acc[g] = fmaf(a.y, w.y, acc[g]);
            acc[g] = fmaf(a.z, w.z, acc[g]);
            acc[g] = fmaf(a.w, w.w, acc[g]);
        }
    }
#pragma unroll
    for (int g = 0; g < 16; g++) out[(size_t)(g0 + g) * 256 + t] = acc[g] + bv;
}

// ---------------------------------------------------------------------------
extern "C" void kernel_launch(void* const* d_in, const int* in_sizes, int n_in,
                              void* d_out, int out_size, void* d_ws, size_t ws_size,
                              hipStream_t stream) {
    const int* a_features = (const int*)d_in[0];
    const int* b_features = (const int*)d_in[1];
    const int* a_scopes   = (const int*)d_in[2];
    const float* emb      = (const float*)d_in[3];
    const float* W_in     = (const float*)d_in[4];
    const float* b_in     = (const float*)d_in[5];
    const float* W_self   = (const float*)d_in[6];
    const float* b_self   = (const float*)d_in[7];
    const float* W_neigh  = (const float*)d_in[8];
    const float* b_neigh  = (const float*)d_in[9];
    const float* W_out    = (const float*)d_in[10];
    const float* b_out    = (const float*)d_in[11];

    if (g_pool == nullptr) {
        fill_kernel<<<(out_size + 255) / 256, 256, 0, stream>>>(
            (float*)d_out, 77777.0f, out_size);
        return;
    }

    // ---- pool layout (halves); interleaved h buffers [hi256|lo256] ----
    f16* p = (f16*)g_pool;
    const size_t HB2 = (size_t)MP * HSTR;        // 153,616,384 halves / buffer
    f16* bufA = p;
    f16* bufB = p + HB2;
    f16* bufC = p + 2 * HB2;
    f16* xbuf = p + 3 * HB2;                     // [MP][64] interleaved
    f16* Winh = xbuf + (size_t)MP * XSTR;
    f16* Winl = Winh + HIDDIM * DCOL;
    f16* Wsh  = Winl + HIDDIM * DCOL;
    f16* Wsl  = Wsh + HIDDIM * HIDDIM;
    f16* Wnh  = Wsl + HIDDIM * HIDDIM;
    f16* Wnl  = Wnh + HIDDIM * HIDDIM;
    float* Gmean = (float*)(Wnl + HIDDIM * HIDDIM);        // [6000][256] fp32
    float* bsum  = Gmean + (size_t)NGRAPHS * HIDDIM;
    int* esrc = (int*)(bsum + HIDDIM);
    int* nxt  = esrc + 2 * NBONDS;
    int* head = nxt + 2 * NBONDS;

    constexpr int NPAD = MP - NATOMS;            // 32 pad rows

    // ---- setup (identical every launch) ----
    hipMemsetAsync(head, 0xFF, (size_t)MP * sizeof(int), stream);
    build_edges_kernel<<<(2 * NBONDS + 255) / 256, 256, 0, stream>>>(b_features, esrc, nxt, head);
    wsplit_kernel<<<(HIDDIM * DCOL + 255) / 256, 256, 0, stream>>>(W_in, Winh, Winl, HIDDIM * DCOL);
    wsplit_kernel<<<(HIDDIM * HIDDIM + 255) / 256, 256, 0, stream>>>(W_self, Wsh, Wsl, HIDDIM * HIDDIM);
    wsplit_kernel<<<(HIDDIM * HIDDIM + 255) / 256, 256, 0, stream>>>(W_neigh, Wnh, Wnl, HIDDIM * HIDDIM);
    bsum_kernel<<<1, HIDDIM, 0, stream>>>(b_self, b_neigh, bsum);

    // Zero padding rows (pool is persistent; keeps pad lanes deterministic).
    constexpr int PADH = NPAD * HSTR / 2;        // halves -> floats
    fill_kernel<<<(PADH + 255) / 256, 256, 0, stream>>>((float*)(bufA + (size_t)NATOMS * HSTR), 0.f, PADH);
    fill_kernel<<<(PADH + 255) / 256, 256, 0, stream>>>((float*)(bufB + (size_t)NATOMS * HSTR), 0.f, PADH);
    fill_kernel<<<(PADH + 255) / 256, 256, 0, stream>>>((float*)(bufC + (size_t)NATOMS * HSTR), 0.f, PADH);
    constexpr int PADX = NPAD * XSTR / 2;
    fill_kernel<<<(PADX + 255) / 256, 256, 0, stream>>>((float*)(xbuf + (size_t)NATOMS * XSTR), 0.f, PADX);

    // ---- embedding + input linear -> h (bufA) ----
    embed_kernel<<<(NATOMS * DCOL + 255) / 256, 256, 0, stream>>>(a_features, emb, xbuf);
    mfma_gemm<false, false, DCOL><<<MTILES128, 512, 0, stream>>>(
        xbuf, nullptr, Winh, Winl, nullptr, nullptr, b_in, bufA);

    // ---- 3 message-passing steps with rotating buffers ----
    f16* h  = bufA;
    f16* g  = bufB;
    f16* hn = bufC;
    for (int s = 0; s < NSTEPS; s++) {
        agg_kernel<<<NATOMS / 4, 256, 0, stream>>>(h, g, head, nxt, esrc);
        mfma_gemm<true, true, HIDDIM><<<MTILES128, 512, 0, stream>>>(
            h, g, Wsh, Wsl, Wnh, Wnl, bsum, hn);
        f16* old = h;
        h = hn; hn = g; g = old;
    }

    // ---- mean first (linearity), then tiny output linear ----
    readout_mean_kernel<<<NGRAPHS, 256, 0, stream>>>(h, a_scopes, Gmean);
    out_gemm_kernel<<<NGRAPHS / 16, 256, 0, stream>>>(Gmean, W_out, b_out, (float*)d_out);
}

// Round 6
// 1781.949 us; speedup vs baseline: 1.1467x; 1.0794x over previous
//
#include <hip/hip_runtime.h>

#define NATOMS 300000
#define NCOLS 8
#define VOCABSZ 4096
#define DCOL 32
#define HIDDIM 256
#define NBONDS 320000
#define NGRAPHS 6000
#define NSTEPS 3

constexpr int MP = 300032;             // atoms padded to multiple of 128
constexpr int MTILES128 = MP / 128;    // 2344 gemm blocks
constexpr int HSTR = 2 * HIDDIM;       // interleaved h row: [hi256|lo256]
constexpr int XSTR = 2 * DCOL;         // interleaved x row: [hi32|lo32]
constexpr int ECAP = 32;               // CSR slots/atom; P(deg>32) < 1e-20

typedef _Float16 f16;
typedef _Float16 f16x8 __attribute__((ext_vector_type(8)));
typedef float f32x4 __attribute__((ext_vector_type(4)));

constexpr float LO_SCALE = 2048.0f;      // 2^11: keeps lo parts fp16-normal
constexpr float INV_LO   = 1.0f / 2048.0f;

__device__ __forceinline__ void split2(float x, f16& h, f16& l) {
    h = (f16)x;
    l = (f16)((x - (float)h) * LO_SCALE);
}

// 16B-unit XOR swizzle (r10: measured ZERO bank conflicts). Involution in q.
__device__ __forceinline__ int swz(int row, int q) {
    return (row * 4 + (q ^ ((row >> 1) & 3))) * 8;
}

// Async global->LDS DMA, 16B per lane per wave-instruction.
__device__ __forceinline__ void dma16(const f16* g, f16* l) {
    __builtin_amdgcn_global_load_lds(
        (const __attribute__((address_space(1))) uint32_t*)g,
        (__attribute__((address_space(3))) uint32_t*)l, 16, 0, 0);
}

// ---------------------------------------------------------------------------
static void* g_pool = nullptr;
__attribute__((constructor)) static void alloc_pool() {
    void* p = nullptr;
    if (hipMalloc(&p, (size_t)1024 * 1024 * 1024) == hipSuccess) {
        hipMemset(p, 0, (size_t)1024 * 1024 * 1024);
        g_pool = p;
    }
}

// ---------------------------------------------------------------------------
__global__ void fill_kernel(float* out, float v, int n) {
    int i = blockIdx.x * blockDim.x + threadIdx.x;
    if (i < n) out[i] = v;
}

// ---------------------------------------------------------------------------
// Bucketed-CSR build: slot = atomicAdd(cnt[dst]); csr[dst*ECAP+slot] = src.
// Replaces the linked list (R5 post-mortem: nxt-chase serialized agg, MLP=1).
__global__ void csr_build_kernel(const int* __restrict__ bf, int* __restrict__ cnt,
                                 int* __restrict__ csr) {
    int e = blockIdx.x * blockDim.x + threadIdx.x;
    if (e >= 2 * NBONDS) return;
    int src, dst;
    if (e < NBONDS) { src = bf[e * 3 + 0]; dst = bf[e * 3 + 1]; }
    else { int i = e - NBONDS; src = bf[i * 3 + 1]; dst = bf[i * 3 + 0]; }
    int slot = atomicAdd(&cnt[dst], 1);
    if (slot < ECAP) csr[dst * ECAP + slot] = src;
}

// ---------------------------------------------------------------------------
__global__ void wsplit_kernel(const float* __restrict__ W, f16* __restrict__ Wh,
                              f16* __restrict__ Wl, int n) {
    int i = blockIdx.x * blockDim.x + threadIdx.x;
    if (i >= n) return;
    split2(W[i], Wh[i], Wl[i]);
}

__global__ void bsum_kernel(const float* __restrict__ a, const float* __restrict__ b,
                            float* __restrict__ o) {
    int i = threadIdx.x;
    o[i] = a[i] + b[i];
}

// ---------------------------------------------------------------------------
// Embedding -> interleaved x rows [hi32|lo32].
__global__ void embed_kernel(const int* __restrict__ af, const float* __restrict__ emb,
                             f16* __restrict__ x) {
    int gid = blockIdx.x * blockDim.x + threadIdx.x;
    int i = gid >> 5, k = gid & 31;
    if (i >= NATOMS) return;
    float s = 0.0f;
#pragma unroll
    for (int c = 0; c < NCOLS; c++) {
        int v = af[i * NCOLS + c];
        int idx = v & (VOCABSZ - 1);
        if (v >= 999999999) idx = 0;
        s += emb[((size_t)c * VOCABSZ + idx) * DCOL + k];
    }
    f16 hi, lo;
    split2(s, hi, lo);
    x[(size_t)i * XSTR + k] = hi;
    x[(size_t)i * XSTR + DCOL + k] = lo;
}

// ---------------------------------------------------------------------------
// Aggregation v2 over bucketed CSR: edge indices are base+j (no nxt-chase),
// unrolled x2 with an int2 slot read -> each iteration issues TWO independent
// 1KB row gathers (MLP 2-4 vs the list's 1, minus two serial latencies/wave).
// Accumulate/butterfly/emit numerics identical to the proven version.
__global__ void agg_kernel(const f16* __restrict__ H, f16* __restrict__ G,
                           const int* __restrict__ cnt, const int* __restrict__ csr) {
    int wid = (blockIdx.x * blockDim.x + threadIdx.x) >> 6;
    int lane = threadIdx.x & 63;
    if (wid >= NATOMS) return;
    float a0 = 0.f, a1 = 0.f, a2 = 0.f, a3 = 0.f,
          a4 = 0.f, a5 = 0.f, a6 = 0.f, a7 = 0.f;
    const int degr = cnt[wid];
    const int deg = degr < ECAP ? degr : ECAP;
    const int* eb = csr + (size_t)wid * ECAP;
    int j = 0;
    for (; j + 2 <= deg; j += 2) {
        const int2 ss = *(const int2*)(eb + j);          // 8B-aligned (j even)
        const f16x8 v0 = *(const f16x8*)(H + (size_t)ss.x * HSTR + lane * 8);
        const f16x8 v1 = *(const f16x8*)(H + (size_t)ss.y * HSTR + lane * 8);
        a0 += (float)v0[0] + (float)v1[0];
        a1 += (float)v0[1] + (float)v1[1];
        a2 += (float)v0[2] + (float)v1[2];
        a3 += (float)v0[3] + (float)v1[3];
        a4 += (float)v0[4] + (float)v1[4];
        a5 += (float)v0[5] + (float)v1[5];
        a6 += (float)v0[6] + (float)v1[6];
        a7 += (float)v0[7] + (float)v1[7];
    }
    if (j < deg) {
        const int s0 = eb[j];
        const f16x8 v = *(const f16x8*)(H + (size_t)s0 * HSTR + lane * 8);
        a0 += (float)v[0]; a1 += (float)v[1]; a2 += (float)v[2]; a3 += (float)v[3];
        a4 += (float)v[4]; a5 += (float)v[5]; a6 += (float)v[6]; a7 += (float)v[7];
    }
    const bool isLo = lane >= 32;
    if (isLo) {
        a0 *= INV_LO; a1 *= INV_LO; a2 *= INV_LO; a3 *= INV_LO;
        a4 *= INV_LO; a5 *= INV_LO; a6 *= INV_LO; a7 *= INV_LO;
    }
    float s0 = a0 + __shfl_xor(a0, 32, 64);
    float s1 = a1 + __shfl_xor(a1, 32, 64);
    float s2 = a2 + __shfl_xor(a2, 32, 64);
    float s3 = a3 + __shfl_xor(a3, 32, 64);
    float s4 = a4 + __shfl_xor(a4, 32, 64);
    float s5 = a5 + __shfl_xor(a5, 32, 64);
    float s6 = a6 + __shfl_xor(a6, 32, 64);
    float s7 = a7 + __shfl_xor(a7, 32, 64);
    f16x8 o;
#define EMIT(J, S)                                                    \
    {                                                                 \
        const f16 hv = (f16)(S);                                      \
        o[J] = isLo ? (f16)(((S) - (float)hv) * LO_SCALE) : hv;       \
    }
    EMIT(0, s0) EMIT(1, s1) EMIT(2, s2) EMIT(3, s3)
    EMIT(4, s4) EMIT(5, s5) EMIT(6, s6) EMIT(7, s7)
#undef EMIT
    *(f16x8*)(G + (size_t)wid * HSTR + lane * 8) = o;
}

// ---------------------------------------------------------------------------
// MFMA GEMM — R4 structure verbatim (best measured: 315us, MfmaUtil 35%):
// depth-2 DMA prefetch, 3x48KB LDS bufs, counted vmcnt(6) at stage barriers
// (vmcnt(0) only at the final stage), monolithic compute stage. R5's
// 3-phase+setprio split REGRESSED (330us) — do not reintroduce.
template <bool HAS_A2, bool RELU, int K>
__global__ __launch_bounds__(512, 2) void mfma_gemm(
    const f16* __restrict__ A1, const f16* __restrict__ A2,
    const f16* __restrict__ B1h, const f16* __restrict__ B1l,
    const f16* __restrict__ B2h, const f16* __restrict__ B2l,
    const float* __restrict__ bias, f16* __restrict__ C) {
    // per-stage buffer (halves): [A-hi 128x32][A-lo][B-hi 256x32][B-lo]
    constexpr int OAH = 0, OAL = 4096, OBH = 8192, OBL = 16384, BUFH = 24576;
    __shared__ __align__(16) f16 lds[3 * BUFH];   // 144 KB

    const int t = threadIdx.x;
    const int m0 = blockIdx.x * 128;
    const int lane = t & 63;
    const int wid = t >> 6;        // 0..7
    const int wr = wid >> 2;       // 0..1 : row  half (64 rows)
    const int wc = wid & 3;        // 0..3 : col quarter (64 cols)
    const int quad = lane >> 4;
    const int l16 = lane & 15;

    // staging geometry: wave w stages rows [w*16, w*16+16), lane -> (row, q)
    const int ra_ = wid * 16 + (lane >> 2);
    const int qs_ = (lane & 3) ^ ((ra_ >> 1) & 3);   // inverse-swizzled quad
    const int ko_ = qs_ * 8;

    f32x4 acch[4][4], accl[4][4];   // [mt][nt]
#pragma unroll
    for (int a = 0; a < 4; a++)
#pragma unroll
        for (int b = 0; b < 4; b++) {
            acch[a][b] = (f32x4){0.f, 0.f, 0.f, 0.f};
            accl[a][b] = (f32x4){0.f, 0.f, 0.f, 0.f};
        }

    constexpr int NMAT = HAS_A2 ? 2 : 1;
    constexpr int NST = (K / 32) * NMAT;

#define ISSUE_STAGE(S, BUF)                                                    \
    {                                                                          \
        const int mat_ = HAS_A2 ? ((S) & 1) : 0;                               \
        const int kb_ = (HAS_A2 ? ((S) >> 1) : (S)) * 32;                      \
        const f16* A_ = (mat_ == 0) ? A1 : A2;                                 \
        const f16* Bh_ = (mat_ == 0) ? B1h : B2h;                              \
        const f16* Bl_ = (mat_ == 0) ? B1l : B2l;                              \
        f16* const dst_ = lds + (BUF) * BUFH + wid * 512;                      \
        const size_t arow_ = (size_t)(m0 + ra_) * (2 * K) + kb_ + ko_;         \
        dma16(A_ + arow_, dst_ + OAH);                                         \
        dma16(A_ + arow_ + K, dst_ + OAL);                                     \
        const size_t brow_ = (size_t)ra_ * K + kb_ + ko_;                      \
        dma16(Bh_ + brow_, dst_ + OBH);                                        \
        dma16(Bh_ + brow_ + (size_t)128 * K, dst_ + OBH + 4096);               \
        dma16(Bl_ + brow_, dst_ + OBL);                                        \
        dma16(Bl_ + brow_ + (size_t)128 * K, dst_ + OBL + 4096);               \
    }

#define COMPUTE_STAGE(BUF)                                                     \
    {                                                                          \
        const f16* cb = lds + (BUF) * BUFH;                                    \
        const f16* sAh = cb + OAH;                                             \
        const f16* sAl = cb + OAL;                                             \
        const f16* sBh = cb + OBH;                                             \
        const f16* sBl = cb + OBL;                                             \
        f16x8 fah[4], fal[4];                                                  \
        _Pragma("unroll")                                                      \
        for (int mt = 0; mt < 4; mt++) {                                       \
            const int src = swz(wr * 64 + mt * 16 + l16, quad);                \
            fah[mt] = *(const f16x8*)(sAh + src);                              \
            fal[mt] = *(const f16x8*)(sAl + src);                              \
        }                                                                      \
        _Pragma("unroll")                                                      \
        for (int nt = 0; nt < 4; nt++) {                                       \
            const int src = swz(wc * 64 + nt * 16 + l16, quad);                \
            const f16x8 bh = *(const f16x8*)(sBh + src);                       \
            const f16x8 bl = *(const f16x8*)(sBl + src);                       \
            _Pragma("unroll")                                                  \
            for (int mt = 0; mt < 4; mt++) {                                   \
                acch[mt][nt] = __builtin_amdgcn_mfma_f32_16x16x32_f16(         \
                    fah[mt], bh, acch[mt][nt], 0, 0, 0);                       \
                accl[mt][nt] = __builtin_amdgcn_mfma_f32_16x16x32_f16(         \
                    fah[mt], bl, accl[mt][nt], 0, 0, 0);                       \
                accl[mt][nt] = __builtin_amdgcn_mfma_f32_16x16x32_f16(         \
                    fal[mt], bh, accl[mt][nt], 0, 0, 0);                       \
            }                                                                  \
        }                                                                      \
    }

    // ---- prologue: depth-2 prefetch into bufs 0 and 1 ----
    ISSUE_STAGE(0, 0);
    asm volatile("" ::: "memory");
    if (NST > 1) ISSUE_STAGE(1, 1);

    int buf = 0;   // s % 3
    for (int s = 0; s < NST - 1; s++) {
        // require DMA(s) retired; allow the 6 newest (= DMA(s+1)) in flight.
        asm volatile("s_waitcnt vmcnt(6) lgkmcnt(0)" ::: "memory");
        __builtin_amdgcn_s_barrier();
        __builtin_amdgcn_sched_barrier(0);
        if (s + 2 < NST) {
            int nb = buf + 2; if (nb >= 3) nb -= 3;
            ISSUE_STAGE(s + 2, nb);
        }
        COMPUTE_STAGE(buf);
        buf = (buf == 2) ? 0 : buf + 1;
    }
    // ---- final stage: nothing younger allowed ----
    asm volatile("s_waitcnt vmcnt(0) lgkmcnt(0)" ::: "memory");
    __builtin_amdgcn_s_barrier();
    __builtin_amdgcn_sched_barrier(0);
    COMPUTE_STAGE(buf);
#undef ISSUE_STAGE
#undef COMPUTE_STAGE

#pragma unroll
    for (int mt = 0; mt < 4; mt++) {
#pragma unroll
        for (int nt = 0; nt < 4; nt++) {
            const int col = wc * 64 + nt * 16 + l16;
            const float bv = bias[col];
#pragma unroll
            for (int r = 0; r < 4; r++) {
                const int row = m0 + wr * 64 + mt * 16 + quad * 4 + r;
                float v = acch[mt][nt][r] + accl[mt][nt][r] * INV_LO + bv;
                if (RELU) v = fmaxf(v, 0.f);
                f16 hi, lo;
                split2(v, hi, lo);
                C[(size_t)row * HSTR + col] = hi;
                C[(size_t)row * HSTR + HIDDIM + col] = lo;
            }
        }
    }
}

// ---------------------------------------------------------------------------
// Segment-mean of interleaved final h -> G[6000][256] fp32.
__global__ void readout_mean_kernel(const f16* __restrict__ H,
                                    const int* __restrict__ scopes, float* __restrict__ G) {
    int g = blockIdx.x;
    int n = threadIdx.x;
    int start = scopes[g * 2 + 0];
    int len = scopes[g * 2 + 1];
    float s = 0.f;
    for (int j = 0; j < len; j++) {
        const f16* row = H + (size_t)(start + j) * HSTR;
        s += (float)row[n] + (float)row[HIDDIM + n] * INV_LO;
    }
    int d = len > 1 ? len : 1;
    G[(size_t)g * HIDDIM + n] = s / (float)d;
}

// ---------------------------------------------------------------------------
// Tiny fp32 GEMM: out[g][n] = G[g][:] . W_out[n][:] + b_out[n], g<6000.
__global__ __launch_bounds__(256) void out_gemm_kernel(
    const float* __restrict__ G, const float* __restrict__ W,
    const float* __restrict__ bias, float* __restrict__ out) {
    __shared__ float sG[16 * 256];
    const int g0 = blockIdx.x * 16;
    const int t = threadIdx.x;
#pragma unroll
    for (int i = 0; i < 16; i++) sG[i * 256 + t] = G[(size_t)(g0 + i) * 256 + t];
    __syncthreads();
    const float bv = bias[t];
    const float* wrow = W + (size_t)t * 256;   // W[n][k] row-major
    float acc[16];
#pragma unroll
    for (int g = 0; g < 16; g++) acc[g] = 0.f;
    for (int k = 0; k < 256; k += 4) {
        const float4 w = *(const float4*)(wrow + k);
#pragma unroll
        for (int g = 0; g < 16; g++) {
            const float4 a = *(const float4*)(sG + g * 256 + k);   // broadcast
            acc[g] = fmaf(a.x, w.x, acc[g]);
            acc[g] = fmaf(a.y, w.y, acc[g]);
            acc[g] = fmaf(a.z, w.z, acc[g]);
            acc[g] = fmaf(a.w, w.w, acc[g]);
        }
    }
#pragma unroll
    for (int g = 0; g < 16; g++) out[(size_t)(g0 + g) * 256 + t] = acc[g] + bv;
}

// ---------------------------------------------------------------------------
extern "C" void kernel_launch(void* const* d_in, const int* in_sizes, int n_in,
                              void* d_out, int out_size, void* d_ws, size_t ws_size,
                              hipStream_t stream) {
    const int* a_features = (const int*)d_in[0];
    const int* b_features = (const int*)d_in[1];
    const int* a_scopes   = (const int*)d_in[2];
    const float* emb      = (const float*)d_in[3];
    const float* W_in     = (const float*)d_in[4];
    const float* b_in     = (const float*)d_in[5];
    const float* W_self   = (const float*)d_in[6];
    const float* b_self   = (const float*)d_in[7];
    const float* W_neigh  = (const float*)d_in[8];
    const float* b_neigh  = (const float*)d_in[9];
    const float* W_out    = (const float*)d_in[10];
    const float* b_out    = (const float*)d_in[11];

    if (g_pool == nullptr) {
        fill_kernel<<<(out_size + 255) / 256, 256, 0, stream>>>(
            (float*)d_out, 77777.0f, out_size);
        return;
    }

    // ---- pool layout (halves); interleaved h buffers [hi256|lo256] ----
    f16* p = (f16*)g_pool;
    const size_t HB2 = (size_t)MP * HSTR;        // 153,616,384 halves / buffer
    f16* bufA = p;
    f16* bufB = p + HB2;
    f16* bufC = p + 2 * HB2;
    f16* xbuf = p + 3 * HB2;                     // [MP][64] interleaved
    f16* Winh = xbuf + (size_t)MP * XSTR;
    f16* Winl = Winh + HIDDIM * DCOL;
    f16* Wsh  = Winl + HIDDIM * DCOL;
    f16* Wsl  = Wsh + HIDDIM * HIDDIM;
    f16* Wnh  = Wsl + HIDDIM * HIDDIM;
    f16* Wnl  = Wnh + HIDDIM * HIDDIM;
    float* Gmean = (float*)(Wnl + HIDDIM * HIDDIM);        // [6000][256] fp32
    float* bsum  = Gmean + (size_t)NGRAPHS * HIDDIM;
    int* csr = (int*)(bsum + HIDDIM);            // [MP][ECAP]
    int* cnt = csr + (size_t)MP * ECAP;          // [MP]

    constexpr int NPAD = MP - NATOMS;            // 32 pad rows

    // ---- setup (identical every launch) ----
    hipMemsetAsync(cnt, 0, (size_t)MP * sizeof(int), stream);
    csr_build_kernel<<<(2 * NBONDS + 255) / 256, 256, 0, stream>>>(b_features, cnt, csr);
    wsplit_kernel<<<(HIDDIM * DCOL + 255) / 256, 256, 0, stream>>>(W_in, Winh, Winl, HIDDIM * DCOL);
    wsplit_kernel<<<(HIDDIM * HIDDIM + 255) / 256, 256, 0, stream>>>(W_self, Wsh, Wsl, HIDDIM * HIDDIM);
    wsplit_kernel<<<(HIDDIM * HIDDIM + 255) / 256, 256, 0, stream>>>(W_neigh, Wnh, Wnl, HIDDIM * HIDDIM);
    bsum_kernel<<<1, HIDDIM, 0, stream>>>(b_self, b_neigh, bsum);

    // Zero padding rows (pool is persistent; keeps pad lanes deterministic).
    constexpr int PADH = NPAD * HSTR / 2;        // halves -> floats
    fill_kernel<<<(PADH + 255) / 256, 256, 0, stream>>>((float*)(bufA + (size_t)NATOMS * HSTR), 0.f, PADH);
    fill_kernel<<<(PADH + 255) / 256, 256, 0, stream>>>((float*)(bufB + (size_t)NATOMS * HSTR), 0.f, PADH);
    fill_kernel<<<(PADH + 255) / 256, 256, 0, stream>>>((float*)(bufC + (size_t)NATOMS * HSTR), 0.f, PADH);
    constexpr int PADX = NPAD * XSTR / 2;
    fill_kernel<<<(PADX + 255) / 256, 256, 0, stream>>>((float*)(xbuf + (size_t)NATOMS * XSTR), 0.f, PADX);

    // ---- embedding + input linear -> h (bufA) ----
    embed_kernel<<<(NATOMS * DCOL + 255) / 256, 256, 0, stream>>>(a_features, emb, xbuf);
    mfma_gemm<false, false, DCOL><<<MTILES128, 512, 0, stream>>>(
        xbuf, nullptr, Winh, Winl, nullptr, nullptr, b_in, bufA);

    // ---- 3 message-passing steps with rotating buffers ----
    f16* h  = bufA;
    f16* g  = bufB;
    f16* hn = bufC;
    for (int s = 0; s < NSTEPS; s++) {
        agg_kernel<<<NATOMS / 4, 256, 0, stream>>>(h, g, cnt, csr);
        mfma_gemm<true, true, HIDDIM><<<MTILES128, 512, 0, stream>>>(
            h, g, Wsh, Wsl, Wnh, Wnl, bsum, hn);
        f16* old = h;
        h = hn; hn = g; g = old;
    }

    // ---- mean first (linearity), then tiny output linear ----
    readout_mean_kernel<<<NGRAPHS, 256, 0, stream>>>(h, a_scopes, Gmean);
    out_gemm_kernel<<<NGRAPHS / 16, 256, 0, stream>>>(Gmean, W_out, b_out, (float*)d_out);
}